// Round 7
// baseline (930.115 us; speedup 1.0000x reference)
//
#include <hip/hip_runtime.h>
#include <hip/hip_fp16.h>

#define N_NODES 50000
#define N_EDGES 800000
#define N_GRAPHS 128
#define JK 576              // 64 + 256 + 256
#define CAP 192
#define NSB ((N_NODES + 255) / 256)   // scan blocks = 196
#define SLICE_U (N_NODES * 16)        // unsigneds per 32-ch slice block

typedef __attribute__((ext_vector_type(8))) short bf16x8;
typedef __attribute__((ext_vector_type(4))) float f32x4;
typedef __attribute__((ext_vector_type(2))) float float2v;
typedef __attribute__((ext_vector_type(2))) unsigned uint2v;

// ---------- bf16 pack/unpack helpers ----------
__device__ __forceinline__ unsigned f2_to_bf2(float a, float b) {
    unsigned ua = __float_as_uint(a), ub = __float_as_uint(b);
    ua = (ua + 0x7fffu + ((ua >> 16) & 1u)) >> 16;       // RNE
    ub = (ub + 0x7fffu + ((ub >> 16) & 1u)) >> 16;
    return ua | (ub << 16);
}
__device__ __forceinline__ uint2 f4_to_bf4(float4 v) {
    return make_uint2(f2_to_bf2(v.x, v.y), f2_to_bf2(v.z, v.w));
}
__device__ __forceinline__ float4 bf4_to_f4(uint2 u) {
    float4 r;
    r.x = __uint_as_float(u.x << 16);
    r.y = __uint_as_float(u.x & 0xffff0000u);
    r.z = __uint_as_float(u.y << 16);
    r.w = __uint_as_float(u.y & 0xffff0000u);
    return r;
}

// ---------- MFMA GEMM: bf16 out = A_bf16 @ B (BT n-major bf16), fp32 acc ----------
// SLA: A is slice-major (8 x [N][32ch]);  SLC: C written slice-major.
template<int BN, int KK, int SLA, int SLC>
__global__ __launch_bounds__(256)
void mfma_gemm(const unsigned short* __restrict__ Abf, int lda,
               const unsigned short* __restrict__ BT,
               unsigned* __restrict__ Cbf, int ldc,
               int M, const float* __restrict__ bias, int relu,
               int a_off, int b_off, int c_off) {
    __shared__ unsigned short As[64][32];
    __shared__ unsigned short Bs[BN][32];
    const int t = threadIdx.x;
    const int wav = t >> 6, lane = t & 63;
    const int quad = lane >> 4, l15 = lane & 15;
    const int m0 = blockIdx.x * 64;
    const int head = blockIdx.y;
    const unsigned short* Ab = Abf + (size_t)head * a_off;
    BT  += (size_t)head * b_off;
    const float* bptr = bias ? bias + (size_t)head * c_off : nullptr;
    unsigned* cbf = Cbf + (((size_t)head * c_off) >> 1);

    f32x4 acc[BN / 16];
#pragma unroll
    for (int i = 0; i < BN / 16; i++) acc[i] = (f32x4){0.f, 0.f, 0.f, 0.f};

    const int arow = t >> 2, aseg = t & 3;
    for (int k0 = 0; k0 < KK; k0 += 32) {
        uint4 av = make_uint4(0, 0, 0, 0);
        int gm = m0 + arow;
        if (gm < M) {
            if (SLA) {
                av = *(const uint4*)&Ab[(size_t)(k0 >> 5) * (N_NODES * 32) +
                                        (size_t)gm * 32 + aseg * 8];
            } else {
                av = *(const uint4*)&Ab[(size_t)gm * lda + k0 + aseg * 8];
            }
        }
        uint4 bv[BN == 256 ? 4 : 1];
        if (BN == 256) {
            const unsigned short* srcb = &BT[(size_t)t * KK + k0];
#pragma unroll
            for (int j = 0; j < 4; j++) bv[j] = *(const uint4*)&srcb[j * 8];
        } else {
            bv[0] = *(const uint4*)&BT[(size_t)arow * KK + k0 + aseg * 8];
        }
        __syncthreads();
        *(uint4*)&As[arow][aseg * 8] = av;
        if (BN == 256) {
#pragma unroll
            for (int j = 0; j < 4; j++) *(uint4*)&Bs[t][j * 8] = bv[j];
        } else {
            *(uint4*)&Bs[arow][aseg * 8] = bv[0];
        }
        __syncthreads();
        bf16x8 afrag = *(const bf16x8*)&As[wav * 16 + l15][quad * 8];
#pragma unroll
        for (int nt = 0; nt < BN / 16; nt++) {
            bf16x8 bfrag = *(const bf16x8*)&Bs[nt * 16 + l15][quad * 8];
            acc[nt] = __builtin_amdgcn_mfma_f32_16x16x32_bf16(afrag, bfrag, acc[nt], 0, 0, 0);
        }
    }
    int rbase = m0 + wav * 16 + quad * 4;
#pragma unroll
    for (int nt = 0; nt < BN / 16; nt++) {
        int col = nt * 16 + l15;
        float bb = bptr ? bptr[col] : 0.f;
#pragma unroll
        for (int r = 0; r < 4; r++) {
            int row = rbase + r;
            float v = acc[nt][r] + bb;
            if (relu) v = fmaxf(v, 0.f);
            float vp = __shfl_xor(v, 1);
            if (row < M && !(l15 & 1)) {
                if (SLC) {
                    int ch = head * c_off + col;
                    size_t a = (size_t)(ch >> 5) * SLICE_U + (size_t)row * 16 + ((ch & 31) >> 1);
                    Cbf[a] = f2_to_bf2(v, vp);
                } else {
                    cbf[((size_t)row * ldc + col) >> 1] = f2_to_bf2(v, vp);
                }
            }
        }
    }
}

// ---------- degree + graph bounds (fused) ----------
__global__ void deg_kernel(const int* __restrict__ dst, int* __restrict__ deg,
                           const int* __restrict__ batch, int* __restrict__ gstart) {
    int t = blockIdx.x * blockDim.x + threadIdx.x;
    if (t < N_EDGES) {
        atomicAdd(&deg[dst[t]], 1);
    } else if (t < N_EDGES + N_NODES) {
        int n = t - N_EDGES;
        int b = batch[n];
        int prev = (n == 0) ? -1 : batch[n - 1];
        for (int g = prev + 1; g <= b; g++) gstart[g] = n;
        if (n == N_NODES - 1)
            for (int g = b + 1; g <= N_GRAPHS; g++) gstart[g] = N_NODES;
    }
}

// ---- fused misc prep: dis | prep_w1 | prep_w2 | W1T | W2T | xbf | pool(x) ----
#define S1 50000
#define S2 50256
#define S3 51280
#define S4 67664
#define S5 133200
#define S6 1733200            // S5 + 50000*32  (xbf pairs)
#define S7 (S6 + 131072)      // + 128 graphs * 4 quarters * 256 threads (x pooling)
__global__ void prep_misc(const int* __restrict__ deg, float* __restrict__ dis,
                          const float* __restrict__ W1, const float* __restrict__ a1s,
                          const float* __restrict__ a1d, float* __restrict__ wes1,
                          float* __restrict__ wed1,
                          const float* __restrict__ W2, const float* __restrict__ a2s,
                          const float* __restrict__ a2d, float* __restrict__ wes2,
                          float* __restrict__ wed2,
                          unsigned short* __restrict__ W1T, unsigned short* __restrict__ W2T,
                          const float* __restrict__ x, unsigned* __restrict__ xbf,
                          const int* __restrict__ gstart, float* __restrict__ psum) {
    int i = blockIdx.x * blockDim.x + threadIdx.x;
    if (i >= S7) return;
    if (i >= S6) {                       // pool x -> psum[:, 0:64]
        int t2 = i - S6;
        int g = t2 >> 10, rem = t2 & 1023;
        int q = rem >> 8, tid = rem & 255;
        int cp = tid & 63, np = tid >> 6;
        int n0 = gstart[g], n1 = gstart[g + 1];
        int len = n1 - n0;
        int ns = n0 + (len * q) / 4, ne = n0 + (len * (q + 1)) / 4;
        float s = 0.f;
        for (int n = ns + np; n < ne; n += 4) s += x[(size_t)n * 64 + cp];
        atomicAdd(&psum[g * JK + cp], s);
    } else if (i >= S5) {                // x -> bf16 (pairs)
        int j = i - S5;
        float2 v = *(const float2*)&x[(size_t)j * 2];
        xbf[j] = f2_to_bf2(v.x, v.y);
    } else if (i >= S4) {                // W2T
        int t2 = i - S4;
        int n = t2 >> 8, c = t2 & 255;
        unsigned u = __float_as_uint(W2[(size_t)c * 256 + n]);
        u = (u + 0x7fffu + ((u >> 16) & 1u)) >> 16;
        W2T[t2] = (unsigned short)u;
    } else if (i >= S3) {                // W1T
        int t2 = i - S3;
        int n = t2 >> 6, c = t2 & 63;
        unsigned u = __float_as_uint(W1[(size_t)c * 256 + n]);
        u = (u + 0x7fffu + ((u >> 16) & 1u)) >> 16;
        W1T[t2] = (unsigned short)u;
    } else if (i >= S2) {                // prep_w2
        int t2 = i - S2;
        int c = t2 >> 2, h = t2 & 3;
        float se = 0.f, sd = 0.f;
        for (int j = 0; j < 64; j++) {
            float w = W2[(size_t)c * 256 + h * 64 + j];
            se += w * a2s[h * 64 + j];
            sd += w * a2d[h * 64 + j];
        }
        wes2[c * 4 + h] = se;
        wed2[c * 4 + h] = sd;
    } else if (i >= S1) {                // prep_w1
        int t2 = i - S1;
        int c = t2 >> 2, h = t2 & 3;
        float se = 0.f, sd = 0.f;
        for (int j = 0; j < 64; j++) {
            float w = W1[(size_t)c * 256 + h * 64 + j];
            se += w * a1s[h * 64 + j];
            sd += w * a1d[h * 64 + j];
        }
        wes1[c * 4 + h] = se;
        wed1[c * 4 + h] = sd;
    } else {                             // dis
        int d = deg[i];
        dis[i] = d > 0 ? rsqrtf((float)d) : 0.f;
    }
}
// ---- hierarchical scan ----
__global__ __launch_bounds__(256) void scan_bsum(const int* __restrict__ deg,
                                                 int* __restrict__ bsum) {
    __shared__ int sd[256];
    int n = blockIdx.x * 256 + threadIdx.x;
    sd[threadIdx.x] = (n < N_NODES) ? deg[n] : 0;
    __syncthreads();
    for (int o = 128; o > 0; o >>= 1) {
        if (threadIdx.x < o) sd[threadIdx.x] += sd[threadIdx.x + o];
        __syncthreads();
    }
    if (threadIdx.x == 0) bsum[blockIdx.x] = sd[0];
}
__global__ __launch_bounds__(256) void scan_bpre(const int* __restrict__ bsum,
                                                 int* __restrict__ bpre,
                                                 int* __restrict__ off_last) {
    __shared__ int sd[256];
    int t = threadIdx.x;
    int v = (t < NSB) ? bsum[t] : 0;
    sd[t] = v;
    __syncthreads();
    for (int o = 1; o < 256; o <<= 1) {
        int u = (t >= o) ? sd[t - o] : 0;
        __syncthreads();
        sd[t] += u;
        __syncthreads();
    }
    if (t < NSB) bpre[t] = sd[t] - v;
    if (t == 255) *off_last = sd[255];
}
__global__ __launch_bounds__(256) void scan_off(const int* __restrict__ deg,
                                                const int* __restrict__ bpre,
                                                int* __restrict__ off) {
    __shared__ int sd[256];
    int n = blockIdx.x * 256 + threadIdx.x;
    int t = threadIdx.x;
    int v = (n < N_NODES) ? deg[n] : 0;
    sd[t] = v;
    __syncthreads();
    for (int o = 1; o < 256; o <<= 1) {
        int u = (t >= o) ? sd[t - o] : 0;
        __syncthreads();
        sd[t] += u;
        __syncthreads();
    }
    if (n < N_NODES) off[n] = bpre[blockIdx.x] + sd[t] - v;
}
// csr_fill also emits packed per-edge records {src:16b | fp16(w):16b} for label
// prop, plus a zero dummy record at N_EDGES (branch-free tail predication).
__global__ void csr_fill(const int* __restrict__ src, const int* __restrict__ dst,
                         const int* __restrict__ off, int* __restrict__ cursor,
                         int* __restrict__ csr_src, unsigned* __restrict__ csr_sw,
                         const float* __restrict__ dis) {
    int e = blockIdx.x * blockDim.x + threadIdx.x;
    if (e == 0) csr_sw[N_EDGES] = 0u;
    if (e >= N_EDGES) return;
    int s = src[e], d = dst[e];
    int pos = off[d] + atomicAdd(&cursor[d], 1);
    csr_src[pos] = s;
    float w = dis[s] * dis[d];
    unsigned hw = (unsigned)__half_as_ushort(__float2half(w));
    csr_sw[pos] = (unsigned)s | (hw << 16);
}

// ---------- es/ed from K=64 fp32 input (x) ----------
__global__ void esed_x(const float* __restrict__ X, const float* __restrict__ wes,
                       const float* __restrict__ wed, float* __restrict__ es,
                       float* __restrict__ ed) {
    int gid = blockIdx.x * blockDim.x + threadIdx.x;
    int n = gid >> 6, lane = threadIdx.x & 63;
    if (n >= N_NODES) return;
    float xv = X[(size_t)n * 64 + lane];
    float4 a = *(const float4*)&wes[lane * 4];
    float4 b = *(const float4*)&wed[lane * 4];
    float4 ps = make_float4(xv * a.x, xv * a.y, xv * a.z, xv * a.w);
    float4 pd = make_float4(xv * b.x, xv * b.y, xv * b.z, xv * b.w);
#pragma unroll
    for (int o = 1; o < 64; o <<= 1) {
        ps.x += __shfl_xor(ps.x, o); ps.y += __shfl_xor(ps.y, o);
        ps.z += __shfl_xor(ps.z, o); ps.w += __shfl_xor(ps.w, o);
        pd.x += __shfl_xor(pd.x, o); pd.y += __shfl_xor(pd.y, o);
        pd.z += __shfl_xor(pd.z, o); pd.w += __shfl_xor(pd.w, o);
    }
    if (lane == 0) {
        *(float4*)&es[n * 4] = ps;
        *(float4*)&ed[n * 4] = pd;
    }
}

// ---------- es/ed for layer 2 from slice-major bf16 h1 ----------
__global__ void esed_h(const unsigned* __restrict__ Hsl, const float* __restrict__ wes,
                       const float* __restrict__ wed, float* __restrict__ es,
                       float* __restrict__ ed) {
    int gid = blockIdx.x * blockDim.x + threadIdx.x;
    int n = gid >> 6, lane = threadIdx.x & 63;
    if (n >= N_NODES) return;
    int sl = lane >> 3;
    uint2v uv = __builtin_nontemporal_load(
        (const uint2v*)&Hsl[(size_t)sl * SLICE_U + (size_t)n * 16 + (lane & 7) * 2]);
    float4 vv = bf4_to_f4(make_uint2(uv.x, uv.y));   // channels ch0..ch0+3, ch0 = lane*4
    float v0 = vv.x, v1 = vv.y, v2 = vv.z, v3 = vv.w;
    int ch0 = lane * 4;
    float4 a0 = *(const float4*)&wes[(ch0 + 0) * 4];
    float4 a1 = *(const float4*)&wes[(ch0 + 1) * 4];
    float4 a2 = *(const float4*)&wes[(ch0 + 2) * 4];
    float4 a3 = *(const float4*)&wes[(ch0 + 3) * 4];
    float4 b0 = *(const float4*)&wed[(ch0 + 0) * 4];
    float4 b1 = *(const float4*)&wed[(ch0 + 1) * 4];
    float4 b2 = *(const float4*)&wed[(ch0 + 2) * 4];
    float4 b3 = *(const float4*)&wed[(ch0 + 3) * 4];
    float4 ps, pd;
    ps.x = v0 * a0.x + v1 * a1.x + v2 * a2.x + v3 * a3.x;
    ps.y = v0 * a0.y + v1 * a1.y + v2 * a2.y + v3 * a3.y;
    ps.z = v0 * a0.z + v1 * a1.z + v2 * a2.z + v3 * a3.z;
    ps.w = v0 * a0.w + v1 * a1.w + v2 * a2.w + v3 * a3.w;
    pd.x = v0 * b0.x + v1 * b1.x + v2 * b2.x + v3 * b3.x;
    pd.y = v0 * b0.y + v1 * b1.y + v2 * b2.y + v3 * b3.y;
    pd.z = v0 * b0.z + v1 * b1.z + v2 * b2.z + v3 * b3.z;
    pd.w = v0 * b0.w + v1 * b1.w + v2 * b2.w + v3 * b3.w;
#pragma unroll
    for (int o = 1; o < 64; o <<= 1) {
        ps.x += __shfl_xor(ps.x, o); ps.y += __shfl_xor(ps.y, o);
        ps.z += __shfl_xor(ps.z, o); ps.w += __shfl_xor(ps.w, o);
        pd.x += __shfl_xor(pd.x, o); pd.y += __shfl_xor(pd.y, o);
        pd.z += __shfl_xor(pd.z, o); pd.w += __shfl_xor(pd.w, o);
    }
    if (lane == 0) {
        *(float4*)&es[n * 4] = ps;
        *(float4*)&ed[n * 4] = pd;
    }
}

// ---------- GAT1: fused softmax + bf16-x aggregation (depth-4 pipeline) ----------
__global__ __launch_bounds__(256)
void gat1_fused(const int* __restrict__ off, const int* __restrict__ csr_src,
                const float* __restrict__ es, const float* __restrict__ ed,
                const unsigned* __restrict__ xbf, unsigned* __restrict__ aggx_bf,
                float* __restrict__ alpha_fb) {
    __shared__ float elds[4][CAP * 4];
    __shared__ int   sidx[4][CAP];
    int wav = threadIdx.x >> 6, lane = threadIdx.x & 63;
    int n = blockIdx.x * 4 + wav;
    bool active = n < N_NODES;
    int p0 = 0, p1 = 0;
    float4 ed4 = make_float4(0.f, 0.f, 0.f, 0.f);
    if (active) { p0 = off[n]; p1 = off[n + 1]; ed4 = *(const float4*)&ed[n * 4]; }
    float4 sum = make_float4(0.f, 0.f, 0.f, 0.f);
    for (int p = p0 + lane; p < p1; p += 64) {
        int s = csr_src[p];
        float4 e4 = *(const float4*)&es[s * 4];
        e4.x += ed4.x; e4.y += ed4.y; e4.z += ed4.z; e4.w += ed4.w;
        e4.x = e4.x > 0.f ? e4.x : 0.2f * e4.x;
        e4.y = e4.y > 0.f ? e4.y : 0.2f * e4.y;
        e4.z = e4.z > 0.f ? e4.z : 0.2f * e4.z;
        e4.w = e4.w > 0.f ? e4.w : 0.2f * e4.w;
        e4.x = __expf(e4.x); e4.y = __expf(e4.y); e4.z = __expf(e4.z); e4.w = __expf(e4.w);
        int q = p - p0;
        if (q < CAP) { *(float4*)&elds[wav][q * 4] = e4; sidx[wav][q] = s; }
        else         *(float4*)&alpha_fb[(size_t)p * 4] = e4;
        sum.x += e4.x; sum.y += e4.y; sum.z += e4.z; sum.w += e4.w;
    }
#pragma unroll
    for (int o = 1; o < 64; o <<= 1) {
        sum.x += __shfl_xor(sum.x, o); sum.y += __shfl_xor(sum.y, o);
        sum.z += __shfl_xor(sum.z, o); sum.w += __shfl_xor(sum.w, o);
    }
    float4 rs;
    rs.x = sum.x > 0.f ? 1.f / sum.x : 0.f;
    rs.y = sum.y > 0.f ? 1.f / sum.y : 0.f;
    rs.z = sum.z > 0.f ? 1.f / sum.z : 0.f;
    rs.w = sum.w > 0.f ? 1.f / sum.w : 0.f;
    if (!active) return;
    int eg = lane >> 4, l15 = lane & 15;
    int deg = p1 - p0;
    float4 a0 = make_float4(0.f, 0.f, 0.f, 0.f);
    float4 a1 = a0, a2 = a0, a3 = a0;
    auto fetch = [&](int qq, float4& e4, float4& xv) {
        e4 = make_float4(0.f, 0.f, 0.f, 0.f);
        xv = e4;
        if (qq < deg) {
            int s;
            if (qq < CAP) { s = sidx[wav][qq]; e4 = *(const float4*)&elds[wav][qq * 4]; }
            else { s = csr_src[p0 + qq]; e4 = *(const float4*)&alpha_fb[(size_t)(p0 + qq) * 4]; }
            xv = bf4_to_f4(*(const uint2*)&xbf[(size_t)s * 32 + l15 * 2]);
        }
    };
    int q = eg;
    float4 eA, xA, eB, xB, eC, xC;
    fetch(q, eA, xA);
    fetch(q + 4, eB, xB);
    fetch(q + 8, eC, xC);
    while (q < deg) {
        float4 eD, xD;
        fetch(q + 12, eD, xD);
        a0.x += eA.x * xA.x; a0.y += eA.x * xA.y; a0.z += eA.x * xA.z; a0.w += eA.x * xA.w;
        a1.x += eA.y * xA.x; a1.y += eA.y * xA.y; a1.z += eA.y * xA.z; a1.w += eA.y * xA.w;
        a2.x += eA.z * xA.x; a2.y += eA.z * xA.y; a2.z += eA.z * xA.z; a2.w += eA.z * xA.w;
        a3.x += eA.w * xA.x; a3.y += eA.w * xA.y; a3.z += eA.w * xA.z; a3.w += eA.w * xA.w;
        eA = eB; xA = xB; eB = eC; xB = xC; eC = eD; xC = xD;
        q += 4;
    }
#pragma unroll
    for (int o = 16; o < 64; o <<= 1) {
        a0.x += __shfl_xor(a0.x, o); a0.y += __shfl_xor(a0.y, o);
        a0.z += __shfl_xor(a0.z, o); a0.w += __shfl_xor(a0.w, o);
        a1.x += __shfl_xor(a1.x, o); a1.y += __shfl_xor(a1.y, o);
        a1.z += __shfl_xor(a1.z, o); a1.w += __shfl_xor(a1.w, o);
        a2.x += __shfl_xor(a2.x, o); a2.y += __shfl_xor(a2.y, o);
        a2.z += __shfl_xor(a2.z, o); a2.w += __shfl_xor(a2.w, o);
        a3.x += __shfl_xor(a3.x, o); a3.y += __shfl_xor(a3.y, o);
        a3.z += __shfl_xor(a3.z, o); a3.w += __shfl_xor(a3.w, o);
    }
    if (eg == 0) {
        a0.x *= rs.x; a0.y *= rs.x; a0.z *= rs.x; a0.w *= rs.x;
        a1.x *= rs.y; a1.y *= rs.y; a1.z *= rs.y; a1.w *= rs.y;
        a2.x *= rs.z; a2.y *= rs.z; a2.z *= rs.z; a2.w *= rs.z;
        a3.x *= rs.w; a3.y *= rs.w; a3.z *= rs.w; a3.w *= rs.w;
        size_t b = (size_t)n * 128 + l15 * 2;
        *(uint2*)&aggx_bf[b +  0] = f4_to_bf4(a0);
        *(uint2*)&aggx_bf[b + 32] = f4_to_bf4(a1);
        *(uint2*)&aggx_bf[b + 64] = f4_to_bf4(a2);
        *(uint2*)&aggx_bf[b + 96] = f4_to_bf4(a3);
    }
}

// ---------- GAT2: fused softmax + bf16 gather; LDS-staged coalesced slice write ----
// N_NODES = 12500*4 exactly -> every block's 4 nodes are valid (no tail guard).
__global__ __launch_bounds__(256)
void gat2_fused(const int* __restrict__ off, const int* __restrict__ csr_src,
                const float* __restrict__ es, const float* __restrict__ ed,
                const unsigned* __restrict__ H2bf, const float* __restrict__ bias,
                unsigned* __restrict__ outbf, float* __restrict__ alpha_fb) {
    __shared__ float elds[4][CAP * 4];
    __shared__ int   sidx[4][CAP];
    __shared__ unsigned stg[4][128];
    int wav = threadIdx.x >> 6, lane = threadIdx.x & 63;
    int n = blockIdx.x * 4 + wav;
    int p0 = off[n], p1 = off[n + 1];
    float4 ed4 = *(const float4*)&ed[n * 4];
    float4 sum = make_float4(0.f, 0.f, 0.f, 0.f);
    for (int p = p0 + lane; p < p1; p += 64) {
        int s = csr_src[p];
        float4 e4 = *(const float4*)&es[s * 4];
        e4.x += ed4.x; e4.y += ed4.y; e4.z += ed4.z; e4.w += ed4.w;
        e4.x = e4.x > 0.f ? e4.x : 0.2f * e4.x;
        e4.y = e4.y > 0.f ? e4.y : 0.2f * e4.y;
        e4.z = e4.z > 0.f ? e4.z : 0.2f * e4.z;
        e4.w = e4.w > 0.f ? e4.w : 0.2f * e4.w;
        e4.x = __expf(e4.x); e4.y = __expf(e4.y); e4.z = __expf(e4.z); e4.w = __expf(e4.w);
        int q = p - p0;
        if (q < CAP) { *(float4*)&elds[wav][q * 4] = e4; sidx[wav][q] = s; }
        else         *(float4*)&alpha_fb[(size_t)p * 4] = e4;
        sum.x += e4.x; sum.y += e4.y; sum.z += e4.z; sum.w += e4.w;
    }
#pragma unroll
    for (int o = 1; o < 64; o <<= 1) {
        sum.x += __shfl_xor(sum.x, o); sum.y += __shfl_xor(sum.y, o);
        sum.z += __shfl_xor(sum.z, o); sum.w += __shfl_xor(sum.w, o);
    }
    int half = lane >> 5, l = lane & 31;
    int hh = l >> 3;
    float sh = (hh == 0) ? sum.x : (hh == 1) ? sum.y : (hh == 2) ? sum.z : sum.w;
    float rsh = sh > 0.f ? 1.f / sh : 0.f;
    int deg = p1 - p0;
    float acc[8];
#pragma unroll
    for (int j = 0; j < 8; j++) acc[j] = 0.f;
    auto fetch = [&](int qq, float& al, uint4& rr) {
        al = 0.f;
        rr = make_uint4(0, 0, 0, 0);
        if (qq < deg) {
            int s;
            if (qq < CAP) { s = sidx[wav][qq]; al = elds[wav][qq * 4 + hh]; }
            else { s = csr_src[p0 + qq]; al = alpha_fb[(size_t)(p0 + qq) * 4 + hh]; }
            rr = *(const uint4*)&H2bf[(size_t)s * 128 + l * 4];
        }
    };
    int q = half;
    float aA, aB, aC;
    uint4 rA, rB, rC;
    fetch(q, aA, rA);
    fetch(q + 2, aB, rB);
    fetch(q + 4, aC, rC);
    while (q < deg) {
        float aD; uint4 rD;
        fetch(q + 6, aD, rD);
        float4 f0 = bf4_to_f4(make_uint2(rA.x, rA.y));
        float4 f1 = bf4_to_f4(make_uint2(rA.z, rA.w));
        acc[0] += aA * f0.x; acc[1] += aA * f0.y; acc[2] += aA * f0.z; acc[3] += aA * f0.w;
        acc[4] += aA * f1.x; acc[5] += aA * f1.y; acc[6] += aA * f1.z; acc[7] += aA * f1.w;
        aA = aB; rA = rB; aB = aC; rB = rC; aC = aD; rC = rD;
        q += 2;
    }
#pragma unroll
    for (int j = 0; j < 8; j++) acc[j] += __shfl_xor(acc[j], 32);
    if (half == 0) {
        float4 b0 = *(const float4*)&bias[l * 8];
        float4 b1 = *(const float4*)&bias[l * 8 + 4];
        float4 o0, o1;
        o0.x = fmaxf(acc[0] * rsh + b0.x, 0.f);
        o0.y = fmaxf(acc[1] * rsh + b0.y, 0.f);
        o0.z = fmaxf(acc[2] * rsh + b0.z, 0.f);
        o0.w = fmaxf(acc[3] * rsh + b0.w, 0.f);
        o1.x = fmaxf(acc[4] * rsh + b1.x, 0.f);
        o1.y = fmaxf(acc[5] * rsh + b1.y, 0.f);
        o1.z = fmaxf(acc[6] * rsh + b1.z, 0.f);
        o1.w = fmaxf(acc[7] * rsh + b1.w, 0.f);
        uint2 w0 = f4_to_bf4(o0), w1 = f4_to_bf4(o1);
        *(uint4*)&stg[wav][l * 4] = make_uint4(w0.x, w0.y, w1.x, w1.y);
    }
    __syncthreads();
    // block-cooperative slice-major write: 256B contiguous per slice per block
    {
        int t = threadIdx.x;
        int s = t >> 5;              // slice 0..7
        int j = t & 31;              // uint2 index: 4 nodes x 16 dwords = 32 uint2
        int node = j >> 3;
        int dw = (j & 7) * 2;
        uint2 v = make_uint2(stg[node][s * 16 + dw], stg[node][s * 16 + dw + 1]);
        *(uint2*)&outbf[(size_t)s * SLICE_U + (size_t)(blockIdx.x * 4 + node) * 16 + dw] = v;
    }
}

// ---------- label prop, slice-partitioned, 4 nodes/wave, packed 4B records ----------
// lane = nsub*16 + e*4 + seg : 4 nodes x 4 edges x 4 x 16B segments.
// Record = {src:16b | fp16(dis[s]*dis[d]):16b}; dummy zero record at N_EDGES.
// Depth-2 pipeline + early residual prefetch + packed-fp32 (v_pk_fma) math.
// Records loaded nontemporal (pure stream, keep slice L2-resident).
__global__ __launch_bounds__(256)
void lp_slice(const int* __restrict__ off, const unsigned* __restrict__ csr_sw,
              const unsigned* __restrict__ in_sl,
              const unsigned* __restrict__ res_sl, unsigned* __restrict__ out_sl) {
    int wav = threadIdx.x >> 6, lane = threadIdx.x & 63;
    int sl = blockIdx.x & 7, chunk = blockIdx.x >> 3;
    int n0c = chunk * 16 + wav * 4;
    int nsub = lane >> 4, e = (lane >> 2) & 3, seg = lane & 3;
    int n = n0c + nsub;
    int p0 = 0, p1 = 0;
    if (n < N_NODES) { p0 = off[n]; p1 = off[n + 1]; }
    // early residual prefetch (e==0 lanes) -- hides HBM latency under edge loop
    size_t aout = (size_t)sl * SLICE_U + (size_t)n * 16 + (seg << 2);
    bool wr = ((lane & 12) == 0) && (n < N_NODES);
    uint4 rres = make_uint4(0, 0, 0, 0);
    if (wr) rres = *(const uint4*)&res_sl[aout];
    int m = (p1 - p0 + 3) >> 2;
    m = max(m, __shfl_xor(m, 16));
    m = max(m, __shfl_xor(m, 32));
    const unsigned* base = in_sl + (size_t)sl * SLICE_U;
    float2v a01 = {0.f, 0.f}, a23 = {0.f, 0.f}, a45 = {0.f, 0.f}, a67 = {0.f, 0.f};
    int p = p0 + e;
    if (m > 0) {
        int peA = (p < p1) ? p : N_EDGES;
        unsigned rA = __builtin_nontemporal_load(&csr_sw[peA]);
        int peB = (p + 4 < p1 && m > 1) ? p + 4 : N_EDGES;
        unsigned rB = __builtin_nontemporal_load(&csr_sw[peB]);
        uint4 dA = *(const uint4*)&base[((rA & 0xffffu) << 4) + (seg << 2)];
        for (int i = 0; i < m; i++) {
            int pn = p + 8;
            int peC = (pn < p1 && i + 2 < m) ? pn : N_EDGES;
            unsigned rC = __builtin_nontemporal_load(&csr_sw[peC]);               // rec, 2 ahead
            uint4 dB = *(const uint4*)&base[((rB & 0xffffu) << 4) + (seg << 2)];  // row, 1 ahead
            float nwf = __half2float(__ushort_as_half((unsigned short)(rA >> 16)));
            float2v nw2 = {nwf, nwf};
            float2v f01, f23, f45, f67;
            f01.x = __uint_as_float(dA.x << 16); f01.y = __uint_as_float(dA.x & 0xffff0000u);
            f23.x = __uint_as_float(dA.y << 16); f23.y = __uint_as_float(dA.y & 0xffff0000u);
            f45.x = __uint_as_float(dA.z << 16); f45.y = __uint_as_float(dA.z & 0xffff0000u);
            f67.x = __uint_as_float(dA.w << 16); f67.y = __uint_as_float(dA.w & 0xffff0000u);
            a01 += nw2 * f01;      // ffp-contract=fast -> v_pk_fma_f32 candidates
            a23 += nw2 * f23;
            a45 += nw2 * f45;
            a67 += nw2 * f67;
            rA = rB; rB = rC; dA = dB;
            p += 4;
        }
    }
#pragma unroll
    for (int o = 4; o <= 8; o <<= 1) {
        a01.x += __shfl_xor(a01.x, o); a01.y += __shfl_xor(a01.y, o);
        a23.x += __shfl_xor(a23.x, o); a23.y += __shfl_xor(a23.y, o);
        a45.x += __shfl_xor(a45.x, o); a45.y += __shfl_xor(a45.y, o);
        a67.x += __shfl_xor(a67.x, o); a67.y += __shfl_xor(a67.y, o);
    }
    if (wr) {   // e == 0: 16 lanes = 4 nodes x 4 segs
        float4 r0 = bf4_to_f4(make_uint2(rres.x, rres.y));
        float4 r1 = bf4_to_f4(make_uint2(rres.z, rres.w));
        float4 o0, o1;
        o0.x = fminf(fmaxf(0.5f * a01.x + 0.5f * r0.x, 0.f), 1.f);
        o0.y = fminf(fmaxf(0.5f * a01.y + 0.5f * r0.y, 0.f), 1.f);
        o0.z = fminf(fmaxf(0.5f * a23.x + 0.5f * r0.z, 0.f), 1.f);
        o0.w = fminf(fmaxf(0.5f * a23.y + 0.5f * r0.w, 0.f), 1.f);
        o1.x = fminf(fmaxf(0.5f * a45.x + 0.5f * r1.x, 0.f), 1.f);
        o1.y = fminf(fmaxf(0.5f * a45.y + 0.5f * r1.y, 0.f), 1.f);
        o1.z = fminf(fmaxf(0.5f * a67.x + 0.5f * r1.z, 0.f), 1.f);
        o1.w = fminf(fmaxf(0.5f * a67.y + 0.5f * r1.w, 0.f), 1.f);
        uint2 w0 = f4_to_bf4(o0), w1 = f4_to_bf4(o1);
        *(uint4*)&out_sl[aout] = make_uint4(w0.x, w0.y, w1.x, w1.y);
    }
}

// ---------- bf16 pool (slice-major input, nontemporal stream) ----------
__global__ void pool_bf(const unsigned* __restrict__ buf, const int* __restrict__ gstart,
                        float* __restrict__ psum, int colOff) {
    int g = blockIdx.x, q = blockIdx.y;
    int n0 = gstart[g], n1 = gstart[g + 1];
    int len = n1 - n0;
    int ns = n0 + (len * q) / 4, ne = n0 + (len * (q + 1)) / 4;
    int cp = threadIdx.x & 127;
    int np = threadIdx.x >> 7;
    size_t sbase = (size_t)(cp >> 4) * SLICE_U + (cp & 15);
    float s0 = 0.f, s1 = 0.f;
    for (int n = ns + np; n < ne; n += 2) {
        unsigned u = __builtin_nontemporal_load(&buf[sbase + (size_t)n * 16]);
        s0 += __uint_as_float(u << 16);
        s1 += __uint_as_float(u & 0xffff0000u);
    }
    atomicAdd(&psum[g * JK + colOff + cp * 2 + 0], s0);
    atomicAdd(&psum[g * JK + colOff + cp * 2 + 1], s1);
}

// ---------- full MLP head: one block per graph ----------
__global__ __launch_bounds__(256)
void head_all(const float* __restrict__ psum, const int* __restrict__ gstart,
              const float* __restrict__ clin,
              const float* __restrict__ pp_w1, const float* __restrict__ pp_b1,
              const float* __restrict__ pp_w2, const float* __restrict__ pp_b2,
              const float* __restrict__ cl_w1, const float* __restrict__ cl_b1,
              const float* __restrict__ cl_w2, const float* __restrict__ cl_b2,
              const float* __restrict__ h_w1, const float* __restrict__ h_b1,
              const float* __restrict__ h_w2, const float* __restrict__ h_b2,
              const float* __restrict__ h_w3, const float* __restrict__ h_b3,
              float* __restrict__ out) {
    __shared__ float zin[JK];
    __shared__ float z1[256];
    __shared__ float zcl[32];
    __shared__ float zc[64];
    __shared__ float z[160];
    __shared__ float z3[64];
    __shared__ float z4[32];
    __shared__ float part[128];
    int g = blockIdx.x, t = threadIdx.x;
    int len = gstart[g + 1] - gstart[g];
    float inv = 1.f / (float)(len > 1 ? len : 1);
    for (int k = t; k < JK; k += 256) zin[k] = psum[g * JK + k] * inv;
    if (t < 32) zcl[t] = clin[g * 32 + t];
    __syncthreads();
    {
        float acc = pp_b1[t];
#pragma unroll 8
        for (int k = 0; k < JK; k++) acc += zin[k] * pp_w1[k * 256 + t];
        z1[t] = fmaxf(acc, 0.f);
    }
    __syncthreads();
    int m = t & 127, half = t >> 7;
    {
        float acc = 0.f;
        int k0 = half * 128;
#pragma unroll 8
        for (int k = k0; k < k0 + 128; k++) acc += z1[k] * pp_w2[k * 128 + m];
        if (half) part[m] = acc;
        __syncthreads();
        if (!half) z[m] = acc + part[m] + pp_b2[m];
    }
    if (t < 64) {
        float acc = cl_b1[t];
#pragma unroll
        for (int k = 0; k < 32; k++) acc += zcl[k] * cl_w1[k * 64 + t];
        zc[t] = fmaxf(acc, 0.f);
    }
    __syncthreads();
    if (t < 32) {
        float acc = cl_b2[t];
#pragma unroll
        for (int k = 0; k < 64; k++) acc += zc[k] * cl_w2[k * 32 + t];
        z[128 + t] = acc;
    }
    __syncthreads();
    if (t < 64) {
        float acc = h_b1[t];
#pragma unroll 8
        for (int k = 0; k < 160; k++) acc += z[k] * h_w1[k * 64 + t];
        z3[t] = fmaxf(acc, 0.f);
    }
    __syncthreads();
    if (t < 32) {
        float acc = h_b2[t];
#pragma unroll
        for (int k = 0; k < 64; k++) acc += z3[k] * h_w2[k * 32 + t];
        z4[t] = fmaxf(acc, 0.f);
    }
    __syncthreads();
    if (t < 2) {
        float acc = h_b3[t];
#pragma unroll
        for (int k = 0; k < 32; k++) acc += z4[k] * h_w3[k * 2 + t];
        out[g * 2 + t] = acc;
    }
}

// ---------- launch ----------
extern "C" void kernel_launch(void* const* d_in, const int* in_sizes, int n_in,
                              void* d_out, int out_size, void* d_ws, size_t ws_size,
                              hipStream_t stream) {
    const float* x     = (const float*)d_in[0];
    const int*   ei    = (const int*)d_in[1];
    const int*   batch = (const int*)d_in[2];
    const float* clin  = (const float*)d_in[3];
    const float* W1  = (const float*)d_in[4];
    const float* a1s = (const float*)d_in[5];
    const float* a1d = (const float*)d_in[6];
    const float* b1  = (const float*)d_in[7];
    const float* W2  = (const float*)d_in[8];
    const float* a2s = (const float*)d_in[9];
    const float* a2d = (const float*)d_in[10];
    const float* b2  = (const float*)d_in[11];
    const float* pp_w1 = (const float*)d_in[12];
    const float* pp_b1 = (const float*)d_in[13];
    const float* pp_w2 = (const float*)d_in[14];
    const float* pp_b2 = (const float*)d_in[15];
    const float* cl_w1 = (const float*)d_in[16];
    const float* cl_b1 = (const float*)d_in[17];
    const float* cl_w2 = (const float*)d_in[18];
    const float* cl_b2 = (const float*)d_in[19];
    const float* h_w1  = (const float*)d_in[20];
    const float* h_b1  = (const float*)d_in[21];
    const float* h_w2  = (const float*)d_in[22];
    const float* h_b2  = (const float*)d_in[23];
    const float* h_w3  = (const float*)d_in[24];
    const float* h_b3  = (const float*)d_in[25];

    const int* src = ei;
    const int* dst = ei + N_EDGES;

    char* p = (char*)d_ws;
    auto carve = [&](size_t bytes) -> char* {
        char* r = p;
        p += (bytes + 255) & ~(size_t)255;
        return r;
    };
    const size_t NBH = (size_t)N_NODES * 256 * 2;    // bf16 node buffer
    unsigned* abf  = (unsigned*)carve(NBH);          // aggx, later h2_final
    unsigned* bf1  = (unsigned*)carve(NBH);
    unsigned* bf2  = (unsigned*)carve(NBH);
    unsigned* bf3  = (unsigned*)carve(NBH);
    unsigned* xbf  = (unsigned*)carve((size_t)N_NODES * 32 * 4);  // bf16 x copy
    float* alpha_fb  = (float*)carve((size_t)N_EDGES * 4 * 4);
    int*   csr_src   = (int*)carve((size_t)N_EDGES * 4);
    unsigned* csr_sw = (unsigned*)carve((size_t)(N_EDGES + 1) * 4); // packed {src,hw} + dummy
    int*   off       = (int*)carve((size_t)(N_NODES + 1) * 4);
    int*   deg       = (int*)carve((size_t)N_NODES * 4);
    int*   cursor    = (int*)carve((size_t)N_NODES * 4);
    int*   bsum      = (int*)carve((size_t)NSB * 4);
    int*   bpre      = (int*)carve((size_t)NSB * 4);
    float* dis       = (float*)carve((size_t)N_NODES * 4);
    float* es        = (float*)carve((size_t)N_NODES * 4 * 4);
    float* ed        = (float*)carve((size_t)N_NODES * 4 * 4);
    float* wes1      = (float*)carve((size_t)64 * 4 * 4);
    float* wed1      = (float*)carve((size_t)64 * 4 * 4);
    float* wes2      = (float*)carve((size_t)256 * 4 * 4);
    float* wed2      = (float*)carve((size_t)256 * 4 * 4);
    unsigned short* W1T = (unsigned short*)carve((size_t)256 * 64 * 2);
    unsigned short* W2T = (unsigned short*)carve((size_t)256 * 256 * 2);
    int*   gstart    = (int*)carve((size_t)(N_GRAPHS + 1) * 4);
    float* psum      = (float*)carve((size_t)N_GRAPHS * JK * 4);

    const int TB = 256;
    const int gE     = (N_EDGES + TB - 1) / TB;
    const int gDeg   = (N_EDGES + N_NODES + TB - 1) / TB;
    const int gNwave = (N_NODES * 64 + TB - 1) / TB;
    const int gFuse  = (N_NODES + 3) / 4;
    const int gRow   = (N_NODES + 63) / 64;
    const int gPrep  = (S7 + TB - 1) / TB;
    const int gSlice = 8 * ((N_NODES + 15) / 16);   // 4 nodes/wave, 16/block, x8 slices

    // ---- CSR + degree + bounds + fused misc prep (incl. x pooling) ----
    hipMemsetAsync(deg, 0, (size_t)N_NODES * 4, stream);
    hipMemsetAsync(cursor, 0, (size_t)N_NODES * 4, stream);
    hipMemsetAsync(psum, 0, (size_t)N_GRAPHS * JK * 4, stream);
    deg_kernel<<<gDeg, TB, 0, stream>>>(dst, deg, batch, gstart);
    prep_misc<<<gPrep, TB, 0, stream>>>(deg, dis,
                                        W1, a1s, a1d, wes1, wed1,
                                        W2, a2s, a2d, wes2, wed2,
                                        W1T, W2T, x, xbf, gstart, psum);
    scan_bsum<<<NSB, 256, 0, stream>>>(deg, bsum);
    scan_bpre<<<1, 256, 0, stream>>>(bsum, bpre, &off[N_NODES]);
    scan_off<<<NSB, 256, 0, stream>>>(deg, bpre, off);
    csr_fill<<<gE, TB, 0, stream>>>(src, dst, off, cursor, csr_src, csr_sw, dis);

    // ---- GAT layer 1 ----
    esed_x<<<gNwave, TB, 0, stream>>>(x, wes1, wed1, es, ed);
    gat1_fused<<<gFuse, TB, 0, stream>>>(off, csr_src, es, ed, xbf, abf, alpha_fb);
    mfma_gemm<64, 64, 0, 1><<<dim3(gRow, 4), 256, 0, stream>>>(
        (const unsigned short*)abf, 256, W1T, bf1, 256, N_NODES, b1, 1,
        64, 64 * 64, 64);                                   // bf1 = h1a (slice-major)

    // ---- label prop 1 (residual = bf1), slice-partitioned ----
    lp_slice<<<gSlice, TB, 0, stream>>>(off, csr_sw, bf1, bf1, bf2);
    lp_slice<<<gSlice, TB, 0, stream>>>(off, csr_sw, bf2, bf1, bf3);  // bf3 = h1
    esed_h<<<gNwave, TB, 0, stream>>>(bf3, wes2, wed2, es, ed);       // layer-2 logits

    pool_bf<<<dim3(N_GRAPHS, 4), TB, 0, stream>>>(bf3, gstart, psum, 64);

    // ---- GAT layer 2 ----
    mfma_gemm<256, 256, 1, 0><<<dim3(gRow, 1), 256, 0, stream>>>(
        (const unsigned short*)bf3, 256, W2T, bf1, 256, N_NODES, nullptr, 0,
        0, 0, 0);                                           // bf1 = h2 (row-major)
    gat2_fused<<<gFuse, TB, 0, stream>>>(off, csr_src, es, ed, bf1, b2, bf2, alpha_fb); // bf2 = h2a (slice-major)

    // ---- label prop 2 (residual = bf2), slice-partitioned ----
    lp_slice<<<gSlice, TB, 0, stream>>>(off, csr_sw, bf2, bf2, bf1);
    lp_slice<<<gSlice, TB, 0, stream>>>(off, csr_sw, bf1, bf2, abf);  // abf = h2_final

    // ---- pooling (h2) + full head ----
    pool_bf<<<dim3(N_GRAPHS, 4), TB, 0, stream>>>(abf, gstart, psum, 320);
    head_all<<<N_GRAPHS, 256, 0, stream>>>(psum, gstart, clin,
                                           pp_w1, pp_b1, pp_w2, pp_b2,
                                           cl_w1, cl_b1, cl_w2, cl_b2,
                                           h_w1, h_b1, h_w2, h_b2, h_w3, h_b3,
                                           (float*)d_out);
}

// Round 8
// 796.950 us; speedup vs baseline: 1.1671x; 1.1671x over previous
//
#include <hip/hip_runtime.h>
#include <hip/hip_fp16.h>

#define N_NODES 50000
#define N_EDGES 800000
#define N_GRAPHS 128
#define JK 576              // 64 + 256 + 256
#define CAP 192
#define NSB ((N_NODES + 255) / 256)   // scan blocks = 196
#define SLICE_U (N_NODES * 16)        // unsigneds per 32-ch slice block

typedef __attribute__((ext_vector_type(8))) short bf16x8;
typedef __attribute__((ext_vector_type(4))) float f32x4;
typedef __attribute__((ext_vector_type(2))) float float2v;

// ---------- bf16 pack/unpack helpers ----------
__device__ __forceinline__ unsigned f2_to_bf2(float a, float b) {
    unsigned ua = __float_as_uint(a), ub = __float_as_uint(b);
    ua = (ua + 0x7fffu + ((ua >> 16) & 1u)) >> 16;       // RNE
    ub = (ub + 0x7fffu + ((ub >> 16) & 1u)) >> 16;
    return ua | (ub << 16);
}
__device__ __forceinline__ uint2 f4_to_bf4(float4 v) {
    return make_uint2(f2_to_bf2(v.x, v.y), f2_to_bf2(v.z, v.w));
}
__device__ __forceinline__ float4 bf4_to_f4(uint2 u) {
    float4 r;
    r.x = __uint_as_float(u.x << 16);
    r.y = __uint_as_float(u.x & 0xffff0000u);
    r.z = __uint_as_float(u.y << 16);
    r.w = __uint_as_float(u.y & 0xffff0000u);
    return r;
}

// ---------- MFMA GEMM: bf16 out = A_bf16 @ B (BT n-major bf16), fp32 acc ----------
// SLA: A is slice-major (8 x [N][32ch]);  SLC: C written slice-major.
template<int BN, int KK, int SLA, int SLC>
__global__ __launch_bounds__(256)
void mfma_gemm(const unsigned short* __restrict__ Abf, int lda,
               const unsigned short* __restrict__ BT,
               unsigned* __restrict__ Cbf, int ldc,
               int M, const float* __restrict__ bias, int relu,
               int a_off, int b_off, int c_off) {
    __shared__ unsigned short As[64][32];
    __shared__ unsigned short Bs[BN][32];
    const int t = threadIdx.x;
    const int wav = t >> 6, lane = t & 63;
    const int quad = lane >> 4, l15 = lane & 15;
    const int m0 = blockIdx.x * 64;
    const int head = blockIdx.y;
    const unsigned short* Ab = Abf + (size_t)head * a_off;
    BT  += (size_t)head * b_off;
    const float* bptr = bias ? bias + (size_t)head * c_off : nullptr;
    unsigned* cbf = Cbf + (((size_t)head * c_off) >> 1);

    f32x4 acc[BN / 16];
#pragma unroll
    for (int i = 0; i < BN / 16; i++) acc[i] = (f32x4){0.f, 0.f, 0.f, 0.f};

    const int arow = t >> 2, aseg = t & 3;
    for (int k0 = 0; k0 < KK; k0 += 32) {
        uint4 av = make_uint4(0, 0, 0, 0);
        int gm = m0 + arow;
        if (gm < M) {
            if (SLA) {
                av = *(const uint4*)&Ab[(size_t)(k0 >> 5) * (N_NODES * 32) +
                                        (size_t)gm * 32 + aseg * 8];
            } else {
                av = *(const uint4*)&Ab[(size_t)gm * lda + k0 + aseg * 8];
            }
        }
        uint4 bv[BN == 256 ? 4 : 1];
        if (BN == 256) {
            const unsigned short* srcb = &BT[(size_t)t * KK + k0];
#pragma unroll
            for (int j = 0; j < 4; j++) bv[j] = *(const uint4*)&srcb[j * 8];
        } else {
            bv[0] = *(const uint4*)&BT[(size_t)arow * KK + k0 + aseg * 8];
        }
        __syncthreads();
        *(uint4*)&As[arow][aseg * 8] = av;
        if (BN == 256) {
#pragma unroll
            for (int j = 0; j < 4; j++) *(uint4*)&Bs[t][j * 8] = bv[j];
        } else {
            *(uint4*)&Bs[arow][aseg * 8] = bv[0];
        }
        __syncthreads();
        bf16x8 afrag = *(const bf16x8*)&As[wav * 16 + l15][quad * 8];
#pragma unroll
        for (int nt = 0; nt < BN / 16; nt++) {
            bf16x8 bfrag = *(const bf16x8*)&Bs[nt * 16 + l15][quad * 8];
            acc[nt] = __builtin_amdgcn_mfma_f32_16x16x32_bf16(afrag, bfrag, acc[nt], 0, 0, 0);
        }
    }
    int rbase = m0 + wav * 16 + quad * 4;
#pragma unroll
    for (int nt = 0; nt < BN / 16; nt++) {
        int col = nt * 16 + l15;
        float bb = bptr ? bptr[col] : 0.f;
#pragma unroll
        for (int r = 0; r < 4; r++) {
            int row = rbase + r;
            float v = acc[nt][r] + bb;
            if (relu) v = fmaxf(v, 0.f);
            float vp = __shfl_xor(v, 1);
            if (row < M && !(l15 & 1)) {
                if (SLC) {
                    int ch = head * c_off + col;
                    size_t a = (size_t)(ch >> 5) * SLICE_U + (size_t)row * 16 + ((ch & 31) >> 1);
                    Cbf[a] = f2_to_bf2(v, vp);
                } else {
                    cbf[((size_t)row * ldc + col) >> 1] = f2_to_bf2(v, vp);
                }
            }
        }
    }
}

// ---------- degree + graph bounds (fused) ----------
__global__ void deg_kernel(const int* __restrict__ dst, int* __restrict__ deg,
                           const int* __restrict__ batch, int* __restrict__ gstart) {
    int t = blockIdx.x * blockDim.x + threadIdx.x;
    if (t < N_EDGES) {
        atomicAdd(&deg[dst[t]], 1);
    } else if (t < N_EDGES + N_NODES) {
        int n = t - N_EDGES;
        int b = batch[n];
        int prev = (n == 0) ? -1 : batch[n - 1];
        for (int g = prev + 1; g <= b; g++) gstart[g] = n;
        if (n == N_NODES - 1)
            for (int g = b + 1; g <= N_GRAPHS; g++) gstart[g] = N_NODES;
    }
}

// ---- fused misc prep: dis | prep_w1 | prep_w2 | W1T | W2T | xbf | pool(x) ----
#define S1 50000
#define S2 50256
#define S3 51280
#define S4 67664
#define S5 133200
#define S6 1733200            // S5 + 50000*32  (xbf pairs)
#define S7 (S6 + 131072)      // + 128 graphs * 4 quarters * 256 threads (x pooling)
__global__ void prep_misc(const int* __restrict__ deg, float* __restrict__ dis,
                          const float* __restrict__ W1, const float* __restrict__ a1s,
                          const float* __restrict__ a1d, float* __restrict__ wes1,
                          float* __restrict__ wed1,
                          const float* __restrict__ W2, const float* __restrict__ a2s,
                          const float* __restrict__ a2d, float* __restrict__ wes2,
                          float* __restrict__ wed2,
                          unsigned short* __restrict__ W1T, unsigned short* __restrict__ W2T,
                          const float* __restrict__ x, unsigned* __restrict__ xbf,
                          const int* __restrict__ gstart, float* __restrict__ psum) {
    int i = blockIdx.x * blockDim.x + threadIdx.x;
    if (i >= S7) return;
    if (i >= S6) {                       // pool x -> psum[:, 0:64]
        int t2 = i - S6;
        int g = t2 >> 10, rem = t2 & 1023;
        int q = rem >> 8, tid = rem & 255;
        int cp = tid & 63, np = tid >> 6;
        int n0 = gstart[g], n1 = gstart[g + 1];
        int len = n1 - n0;
        int ns = n0 + (len * q) / 4, ne = n0 + (len * (q + 1)) / 4;
        float s = 0.f;
        for (int n = ns + np; n < ne; n += 4) s += x[(size_t)n * 64 + cp];
        atomicAdd(&psum[g * JK + cp], s);
    } else if (i >= S5) {                // x -> bf16 (pairs)
        int j = i - S5;
        float2 v = *(const float2*)&x[(size_t)j * 2];
        xbf[j] = f2_to_bf2(v.x, v.y);
    } else if (i >= S4) {                // W2T
        int t2 = i - S4;
        int n = t2 >> 8, c = t2 & 255;
        unsigned u = __float_as_uint(W2[(size_t)c * 256 + n]);
        u = (u + 0x7fffu + ((u >> 16) & 1u)) >> 16;
        W2T[t2] = (unsigned short)u;
    } else if (i >= S3) {                // W1T
        int t2 = i - S3;
        int n = t2 >> 6, c = t2 & 63;
        unsigned u = __float_as_uint(W1[(size_t)c * 256 + n]);
        u = (u + 0x7fffu + ((u >> 16) & 1u)) >> 16;
        W1T[t2] = (unsigned short)u;
    } else if (i >= S2) {                // prep_w2
        int t2 = i - S2;
        int c = t2 >> 2, h = t2 & 3;
        float se = 0.f, sd = 0.f;
        for (int j = 0; j < 64; j++) {
            float w = W2[(size_t)c * 256 + h * 64 + j];
            se += w * a2s[h * 64 + j];
            sd += w * a2d[h * 64 + j];
        }
        wes2[c * 4 + h] = se;
        wed2[c * 4 + h] = sd;
    } else if (i >= S1) {                // prep_w1
        int t2 = i - S1;
        int c = t2 >> 2, h = t2 & 3;
        float se = 0.f, sd = 0.f;
        for (int j = 0; j < 64; j++) {
            float w = W1[(size_t)c * 256 + h * 64 + j];
            se += w * a1s[h * 64 + j];
            sd += w * a1d[h * 64 + j];
        }
        wes1[c * 4 + h] = se;
        wed1[c * 4 + h] = sd;
    } else {                             // dis
        int d = deg[i];
        dis[i] = d > 0 ? rsqrtf((float)d) : 0.f;
    }
}
// ---- hierarchical scan ----
__global__ __launch_bounds__(256) void scan_bsum(const int* __restrict__ deg,
                                                 int* __restrict__ bsum) {
    __shared__ int sd[256];
    int n = blockIdx.x * 256 + threadIdx.x;
    sd[threadIdx.x] = (n < N_NODES) ? deg[n] : 0;
    __syncthreads();
    for (int o = 128; o > 0; o >>= 1) {
        if (threadIdx.x < o) sd[threadIdx.x] += sd[threadIdx.x + o];
        __syncthreads();
    }
    if (threadIdx.x == 0) bsum[blockIdx.x] = sd[0];
}
__global__ __launch_bounds__(256) void scan_bpre(const int* __restrict__ bsum,
                                                 int* __restrict__ bpre,
                                                 int* __restrict__ off_last) {
    __shared__ int sd[256];
    int t = threadIdx.x;
    int v = (t < NSB) ? bsum[t] : 0;
    sd[t] = v;
    __syncthreads();
    for (int o = 1; o < 256; o <<= 1) {
        int u = (t >= o) ? sd[t - o] : 0;
        __syncthreads();
        sd[t] += u;
        __syncthreads();
    }
    if (t < NSB) bpre[t] = sd[t] - v;
    if (t == 255) *off_last = sd[255];
}
__global__ __launch_bounds__(256) void scan_off(const int* __restrict__ deg,
                                                const int* __restrict__ bpre,
                                                int* __restrict__ off) {
    __shared__ int sd[256];
    int n = blockIdx.x * 256 + threadIdx.x;
    int t = threadIdx.x;
    int v = (n < N_NODES) ? deg[n] : 0;
    sd[t] = v;
    __syncthreads();
    for (int o = 1; o < 256; o <<= 1) {
        int u = (t >= o) ? sd[t - o] : 0;
        __syncthreads();
        sd[t] += u;
        __syncthreads();
    }
    if (n < N_NODES) off[n] = bpre[blockIdx.x] + sd[t] - v;
}
// csr_fill also emits packed per-edge records {src:16b | fp16(w):16b} for label
// prop, plus a zero dummy record at N_EDGES (branch-free tail predication).
__global__ void csr_fill(const int* __restrict__ src, const int* __restrict__ dst,
                         const int* __restrict__ off, int* __restrict__ cursor,
                         int* __restrict__ csr_src, unsigned* __restrict__ csr_sw,
                         const float* __restrict__ dis) {
    int e = blockIdx.x * blockDim.x + threadIdx.x;
    if (e == 0) csr_sw[N_EDGES] = 0u;
    if (e >= N_EDGES) return;
    int s = src[e], d = dst[e];
    int pos = off[d] + atomicAdd(&cursor[d], 1);
    csr_src[pos] = s;
    float w = dis[s] * dis[d];
    unsigned hw = (unsigned)__half_as_ushort(__float2half(w));
    csr_sw[pos] = (unsigned)s | (hw << 16);
}

// ---------- es/ed from K=64 fp32 input (x) ----------
__global__ void esed_x(const float* __restrict__ X, const float* __restrict__ wes,
                       const float* __restrict__ wed, float* __restrict__ es,
                       float* __restrict__ ed) {
    int gid = blockIdx.x * blockDim.x + threadIdx.x;
    int n = gid >> 6, lane = threadIdx.x & 63;
    if (n >= N_NODES) return;
    float xv = X[(size_t)n * 64 + lane];
    float4 a = *(const float4*)&wes[lane * 4];
    float4 b = *(const float4*)&wed[lane * 4];
    float4 ps = make_float4(xv * a.x, xv * a.y, xv * a.z, xv * a.w);
    float4 pd = make_float4(xv * b.x, xv * b.y, xv * b.z, xv * b.w);
#pragma unroll
    for (int o = 1; o < 64; o <<= 1) {
        ps.x += __shfl_xor(ps.x, o); ps.y += __shfl_xor(ps.y, o);
        ps.z += __shfl_xor(ps.z, o); ps.w += __shfl_xor(ps.w, o);
        pd.x += __shfl_xor(pd.x, o); pd.y += __shfl_xor(pd.y, o);
        pd.z += __shfl_xor(pd.z, o); pd.w += __shfl_xor(pd.w, o);
    }
    if (lane == 0) {
        *(float4*)&es[n * 4] = ps;
        *(float4*)&ed[n * 4] = pd;
    }
}

// ---------- es/ed for layer 2 from slice-major bf16 h1 ----------
__global__ void esed_h(const unsigned* __restrict__ Hsl, const float* __restrict__ wes,
                       const float* __restrict__ wed, float* __restrict__ es,
                       float* __restrict__ ed) {
    int gid = blockIdx.x * blockDim.x + threadIdx.x;
    int n = gid >> 6, lane = threadIdx.x & 63;
    if (n >= N_NODES) return;
    int sl = lane >> 3;
    uint2 u = *(const uint2*)&Hsl[(size_t)sl * SLICE_U + (size_t)n * 16 + (lane & 7) * 2];
    float4 vv = bf4_to_f4(u);              // channels ch0..ch0+3, ch0 = lane*4
    float v0 = vv.x, v1 = vv.y, v2 = vv.z, v3 = vv.w;
    int ch0 = lane * 4;
    float4 a0 = *(const float4*)&wes[(ch0 + 0) * 4];
    float4 a1 = *(const float4*)&wes[(ch0 + 1) * 4];
    float4 a2 = *(const float4*)&wes[(ch0 + 2) * 4];
    float4 a3 = *(const float4*)&wes[(ch0 + 3) * 4];
    float4 b0 = *(const float4*)&wed[(ch0 + 0) * 4];
    float4 b1 = *(const float4*)&wed[(ch0 + 1) * 4];
    float4 b2 = *(const float4*)&wed[(ch0 + 2) * 4];
    float4 b3 = *(const float4*)&wed[(ch0 + 3) * 4];
    float4 ps, pd;
    ps.x = v0 * a0.x + v1 * a1.x + v2 * a2.x + v3 * a3.x;
    ps.y = v0 * a0.y + v1 * a1.y + v2 * a2.y + v3 * a3.y;
    ps.z = v0 * a0.z + v1 * a1.z + v2 * a2.z + v3 * a3.z;
    ps.w = v0 * a0.w + v1 * a1.w + v2 * a2.w + v3 * a3.w;
    pd.x = v0 * b0.x + v1 * b1.x + v2 * b2.x + v3 * b3.x;
    pd.y = v0 * b0.y + v1 * b1.y + v2 * b2.y + v3 * b3.y;
    pd.z = v0 * b0.z + v1 * b1.z + v2 * b2.z + v3 * b3.z;
    pd.w = v0 * b0.w + v1 * b1.w + v2 * b2.w + v3 * b3.w;
#pragma unroll
    for (int o = 1; o < 64; o <<= 1) {
        ps.x += __shfl_xor(ps.x, o); ps.y += __shfl_xor(ps.y, o);
        ps.z += __shfl_xor(ps.z, o); ps.w += __shfl_xor(ps.w, o);
        pd.x += __shfl_xor(pd.x, o); pd.y += __shfl_xor(pd.y, o);
        pd.w += __shfl_xor(pd.w, o); pd.z += __shfl_xor(pd.z, o);
    }
    if (lane == 0) {
        *(float4*)&es[n * 4] = ps;
        *(float4*)&ed[n * 4] = pd;
    }
}

// ---------- GAT1: fused softmax + bf16-x aggregation (depth-4 pipeline) ----------
__global__ __launch_bounds__(256)
void gat1_fused(const int* __restrict__ off, const int* __restrict__ csr_src,
                const float* __restrict__ es, const float* __restrict__ ed,
                const unsigned* __restrict__ xbf, unsigned* __restrict__ aggx_bf,
                float* __restrict__ alpha_fb) {
    __shared__ float elds[4][CAP * 4];
    __shared__ int   sidx[4][CAP];
    int wav = threadIdx.x >> 6, lane = threadIdx.x & 63;
    int n = blockIdx.x * 4 + wav;
    bool active = n < N_NODES;
    int p0 = 0, p1 = 0;
    float4 ed4 = make_float4(0.f, 0.f, 0.f, 0.f);
    if (active) { p0 = off[n]; p1 = off[n + 1]; ed4 = *(const float4*)&ed[n * 4]; }
    float4 sum = make_float4(0.f, 0.f, 0.f, 0.f);
    for (int p = p0 + lane; p < p1; p += 64) {
        int s = csr_src[p];
        float4 e4 = *(const float4*)&es[s * 4];
        e4.x += ed4.x; e4.y += ed4.y; e4.z += ed4.z; e4.w += ed4.w;
        e4.x = e4.x > 0.f ? e4.x : 0.2f * e4.x;
        e4.y = e4.y > 0.f ? e4.y : 0.2f * e4.y;
        e4.z = e4.z > 0.f ? e4.z : 0.2f * e4.z;
        e4.w = e4.w > 0.f ? e4.w : 0.2f * e4.w;
        e4.x = __expf(e4.x); e4.y = __expf(e4.y); e4.z = __expf(e4.z); e4.w = __expf(e4.w);
        int q = p - p0;
        if (q < CAP) { *(float4*)&elds[wav][q * 4] = e4; sidx[wav][q] = s; }
        else         *(float4*)&alpha_fb[(size_t)p * 4] = e4;
        sum.x += e4.x; sum.y += e4.y; sum.z += e4.z; sum.w += e4.w;
    }
#pragma unroll
    for (int o = 1; o < 64; o <<= 1) {
        sum.x += __shfl_xor(sum.x, o); sum.y += __shfl_xor(sum.y, o);
        sum.z += __shfl_xor(sum.z, o); sum.w += __shfl_xor(sum.w, o);
    }
    float4 rs;
    rs.x = sum.x > 0.f ? 1.f / sum.x : 0.f;
    rs.y = sum.y > 0.f ? 1.f / sum.y : 0.f;
    rs.z = sum.z > 0.f ? 1.f / sum.z : 0.f;
    rs.w = sum.w > 0.f ? 1.f / sum.w : 0.f;
    if (!active) return;
    int eg = lane >> 4, l15 = lane & 15;
    int deg = p1 - p0;
    float4 a0 = make_float4(0.f, 0.f, 0.f, 0.f);
    float4 a1 = a0, a2 = a0, a3 = a0;
    auto fetch = [&](int qq, float4& e4, float4& xv) {
        e4 = make_float4(0.f, 0.f, 0.f, 0.f);
        xv = e4;
        if (qq < deg) {
            int s;
            if (qq < CAP) { s = sidx[wav][qq]; e4 = *(const float4*)&elds[wav][qq * 4]; }
            else { s = csr_src[p0 + qq]; e4 = *(const float4*)&alpha_fb[(size_t)(p0 + qq) * 4]; }
            xv = bf4_to_f4(*(const uint2*)&xbf[(size_t)s * 32 + l15 * 2]);
        }
    };
    int q = eg;
    float4 eA, xA, eB, xB, eC, xC;
    fetch(q, eA, xA);
    fetch(q + 4, eB, xB);
    fetch(q + 8, eC, xC);
    while (q < deg) {
        float4 eD, xD;
        fetch(q + 12, eD, xD);
        a0.x += eA.x * xA.x; a0.y += eA.x * xA.y; a0.z += eA.x * xA.z; a0.w += eA.x * xA.w;
        a1.x += eA.y * xA.x; a1.y += eA.y * xA.y; a1.z += eA.y * xA.z; a1.w += eA.y * xA.w;
        a2.x += eA.z * xA.x; a2.y += eA.z * xA.y; a2.z += eA.z * xA.z; a2.w += eA.z * xA.w;
        a3.x += eA.w * xA.x; a3.y += eA.w * xA.y; a3.z += eA.w * xA.z; a3.w += eA.w * xA.w;
        eA = eB; xA = xB; eB = eC; xB = xC; eC = eD; xC = xD;
        q += 4;
    }
#pragma unroll
    for (int o = 16; o < 64; o <<= 1) {
        a0.x += __shfl_xor(a0.x, o); a0.y += __shfl_xor(a0.y, o);
        a0.z += __shfl_xor(a0.z, o); a0.w += __shfl_xor(a0.w, o);
        a1.x += __shfl_xor(a1.x, o); a1.y += __shfl_xor(a1.y, o);
        a1.z += __shfl_xor(a1.z, o); a1.w += __shfl_xor(a1.w, o);
        a2.x += __shfl_xor(a2.x, o); a2.y += __shfl_xor(a2.y, o);
        a2.z += __shfl_xor(a2.z, o); a2.w += __shfl_xor(a2.w, o);
        a3.x += __shfl_xor(a3.x, o); a3.y += __shfl_xor(a3.y, o);
        a3.z += __shfl_xor(a3.z, o); a3.w += __shfl_xor(a3.w, o);
    }
    if (eg == 0) {
        a0.x *= rs.x; a0.y *= rs.x; a0.z *= rs.x; a0.w *= rs.x;
        a1.x *= rs.y; a1.y *= rs.y; a1.z *= rs.y; a1.w *= rs.y;
        a2.x *= rs.z; a2.y *= rs.z; a2.z *= rs.z; a2.w *= rs.z;
        a3.x *= rs.w; a3.y *= rs.w; a3.z *= rs.w; a3.w *= rs.w;
        size_t b = (size_t)n * 128 + l15 * 2;
        *(uint2*)&aggx_bf[b +  0] = f4_to_bf4(a0);
        *(uint2*)&aggx_bf[b + 32] = f4_to_bf4(a1);
        *(uint2*)&aggx_bf[b + 64] = f4_to_bf4(a2);
        *(uint2*)&aggx_bf[b + 96] = f4_to_bf4(a3);
    }
}

// ---------- GAT2: fused softmax + bf16 gather; LDS-staged coalesced slice write ----
// N_NODES = 12500*4 exactly -> every block's 4 nodes are valid (no tail guard).
__global__ __launch_bounds__(256)
void gat2_fused(const int* __restrict__ off, const int* __restrict__ csr_src,
                const float* __restrict__ es, const float* __restrict__ ed,
                const unsigned* __restrict__ H2bf, const float* __restrict__ bias,
                unsigned* __restrict__ outbf, float* __restrict__ alpha_fb) {
    __shared__ float elds[4][CAP * 4];
    __shared__ int   sidx[4][CAP];
    __shared__ unsigned stg[4][128];
    int wav = threadIdx.x >> 6, lane = threadIdx.x & 63;
    int n = blockIdx.x * 4 + wav;
    int p0 = off[n], p1 = off[n + 1];
    float4 ed4 = *(const float4*)&ed[n * 4];
    float4 sum = make_float4(0.f, 0.f, 0.f, 0.f);
    for (int p = p0 + lane; p < p1; p += 64) {
        int s = csr_src[p];
        float4 e4 = *(const float4*)&es[s * 4];
        e4.x += ed4.x; e4.y += ed4.y; e4.z += ed4.z; e4.w += ed4.w;
        e4.x = e4.x > 0.f ? e4.x : 0.2f * e4.x;
        e4.y = e4.y > 0.f ? e4.y : 0.2f * e4.y;
        e4.z = e4.z > 0.f ? e4.z : 0.2f * e4.z;
        e4.w = e4.w > 0.f ? e4.w : 0.2f * e4.w;
        e4.x = __expf(e4.x); e4.y = __expf(e4.y); e4.z = __expf(e4.z); e4.w = __expf(e4.w);
        int q = p - p0;
        if (q < CAP) { *(float4*)&elds[wav][q * 4] = e4; sidx[wav][q] = s; }
        else         *(float4*)&alpha_fb[(size_t)p * 4] = e4;
        sum.x += e4.x; sum.y += e4.y; sum.z += e4.z; sum.w += e4.w;
    }
#pragma unroll
    for (int o = 1; o < 64; o <<= 1) {
        sum.x += __shfl_xor(sum.x, o); sum.y += __shfl_xor(sum.y, o);
        sum.z += __shfl_xor(sum.z, o); sum.w += __shfl_xor(sum.w, o);
    }
    int half = lane >> 5, l = lane & 31;
    int hh = l >> 3;
    float sh = (hh == 0) ? sum.x : (hh == 1) ? sum.y : (hh == 2) ? sum.z : sum.w;
    float rsh = sh > 0.f ? 1.f / sh : 0.f;
    int deg = p1 - p0;
    float acc[8];
#pragma unroll
    for (int j = 0; j < 8; j++) acc[j] = 0.f;
    auto fetch = [&](int qq, float& al, uint4& rr) {
        al = 0.f;
        rr = make_uint4(0, 0, 0, 0);
        if (qq < deg) {
            int s;
            if (qq < CAP) { s = sidx[wav][qq]; al = elds[wav][qq * 4 + hh]; }
            else { s = csr_src[p0 + qq]; al = alpha_fb[(size_t)(p0 + qq) * 4 + hh]; }
            rr = *(const uint4*)&H2bf[(size_t)s * 128 + l * 4];
        }
    };
    int q = half;
    float aA, aB, aC;
    uint4 rA, rB, rC;
    fetch(q, aA, rA);
    fetch(q + 2, aB, rB);
    fetch(q + 4, aC, rC);
    while (q < deg) {
        float aD; uint4 rD;
        fetch(q + 6, aD, rD);
        float4 f0 = bf4_to_f4(make_uint2(rA.x, rA.y));
        float4 f1 = bf4_to_f4(make_uint2(rA.z, rA.w));
        acc[0] += aA * f0.x; acc[1] += aA * f0.y; acc[2] += aA * f0.z; acc[3] += aA * f0.w;
        acc[4] += aA * f1.x; acc[5] += aA * f1.y; acc[6] += aA * f1.z; acc[7] += aA * f1.w;
        aA = aB; rA = rB; aB = aC; rB = rC; aC = aD; rC = rD;
        q += 2;
    }
#pragma unroll
    for (int j = 0; j < 8; j++) acc[j] += __shfl_xor(acc[j], 32);
    if (half == 0) {
        float4 b0 = *(const float4*)&bias[l * 8];
        float4 b1 = *(const float4*)&bias[l * 8 + 4];
        float4 o0, o1;
        o0.x = fmaxf(acc[0] * rsh + b0.x, 0.f);
        o0.y = fmaxf(acc[1] * rsh + b0.y, 0.f);
        o0.z = fmaxf(acc[2] * rsh + b0.z, 0.f);
        o0.w = fmaxf(acc[3] * rsh + b0.w, 0.f);
        o1.x = fmaxf(acc[4] * rsh + b1.x, 0.f);
        o1.y = fmaxf(acc[5] * rsh + b1.y, 0.f);
        o1.z = fmaxf(acc[6] * rsh + b1.z, 0.f);
        o1.w = fmaxf(acc[7] * rsh + b1.w, 0.f);
        uint2 w0 = f4_to_bf4(o0), w1 = f4_to_bf4(o1);
        *(uint4*)&stg[wav][l * 4] = make_uint4(w0.x, w0.y, w1.x, w1.y);
    }
    __syncthreads();
    // block-cooperative slice-major write: 256B contiguous per slice per block
    {
        int t = threadIdx.x;
        int s = t >> 5;              // slice 0..7
        int j = t & 31;              // uint2 index: 4 nodes x 16 dwords = 32 uint2
        int node = j >> 3;
        int dw = (j & 7) * 2;
        uint2 v = make_uint2(stg[node][s * 16 + dw], stg[node][s * 16 + dw + 1]);
        *(uint2*)&outbf[(size_t)s * SLICE_U + (size_t)(blockIdx.x * 4 + node) * 16 + dw] = v;
    }
}

// ---------- label prop, slice-partitioned, 4 nodes/wave, packed 4B records ----------
// lane = nsub*16 + e*4 + seg : 4 nodes x 4 edges x 4 x 16B segments.
// Record = {src:16b | fp16(dis[s]*dis[d]):16b}; dummy zero record at N_EDGES.
// Unroll-by-2 ping-pong pipeline (no rotation moves) + packed fp32 accumulate.
__global__ __launch_bounds__(256)
void lp_slice(const int* __restrict__ off, const unsigned* __restrict__ csr_sw,
              const unsigned* __restrict__ in_sl,
              const unsigned* __restrict__ res_sl, unsigned* __restrict__ out_sl) {
    int wav = threadIdx.x >> 6, lane = threadIdx.x & 63;
    int sl = blockIdx.x & 7, chunk = blockIdx.x >> 3;
    int n0c = chunk * 16 + wav * 4;
    int nsub = lane >> 4, e = (lane >> 2) & 3, seg = lane & 3;
    int n = n0c + nsub;
    int p0 = 0, p1 = 0;
    if (n < N_NODES) { p0 = off[n]; p1 = off[n + 1]; }
    int m = (p1 - p0 + 3) >> 2;
    m = max(m, __shfl_xor(m, 16));
    m = max(m, __shfl_xor(m, 32));
    const unsigned* base = in_sl + (size_t)sl * SLICE_U;
    float2v a01 = {0.f, 0.f}, a23 = {0.f, 0.f}, a45 = {0.f, 0.f}, a67 = {0.f, 0.f};
    int p = p0 + e;
#define LP_ACC(rr, dd)                                                                        \
    {                                                                                         \
        float nwf = __half2float(__ushort_as_half((unsigned short)((rr) >> 16)));             \
        float2v nw2 = {nwf, nwf};                                                             \
        float2v f01, f23, f45, f67;                                                           \
        f01.x = __uint_as_float((dd).x << 16); f01.y = __uint_as_float((dd).x & 0xffff0000u); \
        f23.x = __uint_as_float((dd).y << 16); f23.y = __uint_as_float((dd).y & 0xffff0000u); \
        f45.x = __uint_as_float((dd).z << 16); f45.y = __uint_as_float((dd).z & 0xffff0000u); \
        f67.x = __uint_as_float((dd).w << 16); f67.y = __uint_as_float((dd).w & 0xffff0000u); \
        a01 += nw2 * f01; a23 += nw2 * f23; a45 += nw2 * f45; a67 += nw2 * f67;               \
    }
    if (m > 0) {
        int pe0 = (p < p1) ? p : N_EDGES;
        unsigned rA = csr_sw[pe0];
        int pe1 = (p + 4 < p1) ? p + 4 : N_EDGES;
        unsigned rB = csr_sw[pe1];
        uint4 dA = *(const uint4*)&base[((rA & 0xffffu) << 4) + (seg << 2)];
        int i = 0;
        for (; i + 2 <= m; i += 2) {
            int pe2 = (p + 8 < p1) ? p + 8 : N_EDGES;
            unsigned rC = csr_sw[pe2];                                            // rec i+2
            uint4 dB = *(const uint4*)&base[((rB & 0xffffu) << 4) + (seg << 2)];  // row i+1
            LP_ACC(rA, dA);                                                       // edge i
            int pe3 = (p + 12 < p1) ? p + 12 : N_EDGES;
            unsigned rD = csr_sw[pe3];                                            // rec i+3
            dA = *(const uint4*)&base[((rC & 0xffffu) << 4) + (seg << 2)];        // row i+2
            LP_ACC(rB, dB);                                                       // edge i+1
            rA = rC; rB = rD;
            p += 8;
        }
        if (i < m) LP_ACC(rA, dA);                                                // odd tail
    }
#undef LP_ACC
#pragma unroll
    for (int o = 4; o <= 8; o <<= 1) {
        a01.x += __shfl_xor(a01.x, o); a01.y += __shfl_xor(a01.y, o);
        a23.x += __shfl_xor(a23.x, o); a23.y += __shfl_xor(a23.y, o);
        a45.x += __shfl_xor(a45.x, o); a45.y += __shfl_xor(a45.y, o);
        a67.x += __shfl_xor(a67.x, o); a67.y += __shfl_xor(a67.y, o);
    }
    if (((lane & 12) == 0) && n < N_NODES) {   // e == 0: 16 lanes = 4 nodes x 4 segs
        size_t a = (size_t)sl * SLICE_U + (size_t)n * 16 + (seg << 2);
        uint4 rr = *(const uint4*)&res_sl[a];
        float4 r0 = bf4_to_f4(make_uint2(rr.x, rr.y));
        float4 r1 = bf4_to_f4(make_uint2(rr.z, rr.w));
        float4 o0, o1;
        o0.x = fminf(fmaxf(0.5f * a01.x + 0.5f * r0.x, 0.f), 1.f);
        o0.y = fminf(fmaxf(0.5f * a01.y + 0.5f * r0.y, 0.f), 1.f);
        o0.z = fminf(fmaxf(0.5f * a23.x + 0.5f * r0.z, 0.f), 1.f);
        o0.w = fminf(fmaxf(0.5f * a23.y + 0.5f * r0.w, 0.f), 1.f);
        o1.x = fminf(fmaxf(0.5f * a45.x + 0.5f * r1.x, 0.f), 1.f);
        o1.y = fminf(fmaxf(0.5f * a45.y + 0.5f * r1.y, 0.f), 1.f);
        o1.z = fminf(fmaxf(0.5f * a67.x + 0.5f * r1.z, 0.f), 1.f);
        o1.w = fminf(fmaxf(0.5f * a67.y + 0.5f * r1.w, 0.f), 1.f);
        uint2 w0 = f4_to_bf4(o0), w1 = f4_to_bf4(o1);
        *(uint4*)&out_sl[a] = make_uint4(w0.x, w0.y, w1.x, w1.y);
    }
}

// ---------- bf16 pool (slice-major input) ----------
__global__ void pool_bf(const unsigned* __restrict__ buf, const int* __restrict__ gstart,
                        float* __restrict__ psum, int colOff) {
    int g = blockIdx.x, q = blockIdx.y;
    int n0 = gstart[g], n1 = gstart[g + 1];
    int len = n1 - n0;
    int ns = n0 + (len * q) / 4, ne = n0 + (len * (q + 1)) / 4;
    int cp = threadIdx.x & 127;
    int np = threadIdx.x >> 7;
    size_t sbase = (size_t)(cp >> 4) * SLICE_U + (cp & 15);
    float s0 = 0.f, s1 = 0.f;
    for (int n = ns + np; n < ne; n += 2) {
        unsigned u = buf[sbase + (size_t)n * 16];
        s0 += __uint_as_float(u << 16);
        s1 += __uint_as_float(u & 0xffff0000u);
    }
    atomicAdd(&psum[g * JK + colOff + cp * 2 + 0], s0);
    atomicAdd(&psum[g * JK + colOff + cp * 2 + 1], s1);
}

// ---------- full MLP head: one block per graph ----------
__global__ __launch_bounds__(256)
void head_all(const float* __restrict__ psum, const int* __restrict__ gstart,
              const float* __restrict__ clin,
              const float* __restrict__ pp_w1, const float* __restrict__ pp_b1,
              const float* __restrict__ pp_w2, const float* __restrict__ pp_b2,
              const float* __restrict__ cl_w1, const float* __restrict__ cl_b1,
              const float* __restrict__ cl_w2, const float* __restrict__ cl_b2,
              const float* __restrict__ h_w1, const float* __restrict__ h_b1,
              const float* __restrict__ h_w2, const float* __restrict__ h_b2,
              const float* __restrict__ h_w3, const float* __restrict__ h_b3,
              float* __restrict__ out) {
    __shared__ float zin[JK];
    __shared__ float z1[256];
    __shared__ float zcl[32];
    __shared__ float zc[64];
    __shared__ float z[160];
    __shared__ float z3[64];
    __shared__ float z4[32];
    __shared__ float part[128];
    int g = blockIdx.x, t = threadIdx.x;
    int len = gstart[g + 1] - gstart[g];
    float inv = 1.f / (float)(len > 1 ? len : 1);
    for (int k = t; k < JK; k += 256) zin[k] = psum[g * JK + k] * inv;
    if (t < 32) zcl[t] = clin[g * 32 + t];
    __syncthreads();
    {
        float acc = pp_b1[t];
#pragma unroll 8
        for (int k = 0; k < JK; k++) acc += zin[k] * pp_w1[k * 256 + t];
        z1[t] = fmaxf(acc, 0.f);
    }
    __syncthreads();
    int m = t & 127, half = t >> 7;
    {
        float acc = 0.f;
        int k0 = half * 128;
#pragma unroll 8
        for (int k = k0; k < k0 + 128; k++) acc += z1[k] * pp_w2[k * 128 + m];
        if (half) part[m] = acc;
        __syncthreads();
        if (!half) z[m] = acc + part[m] + pp_b2[m];
    }
    if (t < 64) {
        float acc = cl_b1[t];
#pragma unroll
        for (int k = 0; k < 32; k++) acc += zcl[k] * cl_w1[k * 64 + t];
        zc[t] = fmaxf(acc, 0.f);
    }
    __syncthreads();
    if (t < 32) {
        float acc = cl_b2[t];
#pragma unroll
        for (int k = 0; k < 64; k++) acc += zc[k] * cl_w2[k * 32 + t];
        z[128 + t] = acc;
    }
    __syncthreads();
    if (t < 64) {
        float acc = h_b1[t];
#pragma unroll 8
        for (int k = 0; k < 160; k++) acc += z[k] * h_w1[k * 64 + t];
        z3[t] = fmaxf(acc, 0.f);
    }
    __syncthreads();
    if (t < 32) {
        float acc = h_b2[t];
#pragma unroll
        for (int k = 0; k < 64; k++) acc += z3[k] * h_w2[k * 32 + t];
        z4[t] = fmaxf(acc, 0.f);
    }
    __syncthreads();
    if (t < 2) {
        float acc = h_b3[t];
#pragma unroll
        for (int k = 0; k < 32; k++) acc += z4[k] * h_w3[k * 2 + t];
        out[g * 2 + t] = acc;
    }
}

// ---------- launch ----------
extern "C" void kernel_launch(void* const* d_in, const int* in_sizes, int n_in,
                              void* d_out, int out_size, void* d_ws, size_t ws_size,
                              hipStream_t stream) {
    const float* x     = (const float*)d_in[0];
    const int*   ei    = (const int*)d_in[1];
    const int*   batch = (const int*)d_in[2];
    const float* clin  = (const float*)d_in[3];
    const float* W1  = (const float*)d_in[4];
    const float* a1s = (const float*)d_in[5];
    const float* a1d = (const float*)d_in[6];
    const float* b1  = (const float*)d_in[7];
    const float* W2  = (const float*)d_in[8];
    const float* a2s = (const float*)d_in[9];
    const float* a2d = (const float*)d_in[10];
    const float* b2  = (const float*)d_in[11];
    const float* pp_w1 = (const float*)d_in[12];
    const float* pp_b1 = (const float*)d_in[13];
    const float* pp_w2 = (const float*)d_in[14];
    const float* pp_b2 = (const float*)d_in[15];
    const float* cl_w1 = (const float*)d_in[16];
    const float* cl_b1 = (const float*)d_in[17];
    const float* cl_w2 = (const float*)d_in[18];
    const float* cl_b2 = (const float*)d_in[19];
    const float* h_w1  = (const float*)d_in[20];
    const float* h_b1  = (const float*)d_in[21];
    const float* h_w2  = (const float*)d_in[22];
    const float* h_b2  = (const float*)d_in[23];
    const float* h_w3  = (const float*)d_in[24];
    const float* h_b3  = (const float*)d_in[25];

    const int* src = ei;
    const int* dst = ei + N_EDGES;

    char* p = (char*)d_ws;
    auto carve = [&](size_t bytes) -> char* {
        char* r = p;
        p += (bytes + 255) & ~(size_t)255;
        return r;
    };
    const size_t NBH = (size_t)N_NODES * 256 * 2;    // bf16 node buffer
    unsigned* abf  = (unsigned*)carve(NBH);          // aggx, later h2_final
    unsigned* bf1  = (unsigned*)carve(NBH);
    unsigned* bf2  = (unsigned*)carve(NBH);
    unsigned* bf3  = (unsigned*)carve(NBH);
    unsigned* xbf  = (unsigned*)carve((size_t)N_NODES * 32 * 4);  // bf16 x copy
    float* alpha_fb  = (float*)carve((size_t)N_EDGES * 4 * 4);
    int*   csr_src   = (int*)carve((size_t)N_EDGES * 4);
    unsigned* csr_sw = (unsigned*)carve((size_t)(N_EDGES + 1) * 4); // packed {src,hw} + dummy
    int*   off       = (int*)carve((size_t)(N_NODES + 1) * 4);
    int*   deg       = (int*)carve((size_t)N_NODES * 4);
    int*   cursor    = (int*)carve((size_t)N_NODES * 4);
    int*   bsum      = (int*)carve((size_t)NSB * 4);
    int*   bpre      = (int*)carve((size_t)NSB * 4);
    float* dis       = (float*)carve((size_t)N_NODES * 4);
    float* es        = (float*)carve((size_t)N_NODES * 4 * 4);
    float* ed        = (float*)carve((size_t)N_NODES * 4 * 4);
    float* wes1      = (float*)carve((size_t)64 * 4 * 4);
    float* wed1      = (float*)carve((size_t)64 * 4 * 4);
    float* wes2      = (float*)carve((size_t)256 * 4 * 4);
    float* wed2      = (float*)carve((size_t)256 * 4 * 4);
    unsigned short* W1T = (unsigned short*)carve((size_t)256 * 64 * 2);
    unsigned short* W2T = (unsigned short*)carve((size_t)256 * 256 * 2);
    int*   gstart    = (int*)carve((size_t)(N_GRAPHS + 1) * 4);
    float* psum      = (float*)carve((size_t)N_GRAPHS * JK * 4);

    const int TB = 256;
    const int gE     = (N_EDGES + TB - 1) / TB;
    const int gDeg   = (N_EDGES + N_NODES + TB - 1) / TB;
    const int gNwave = (N_NODES * 64 + TB - 1) / TB;
    const int gFuse  = (N_NODES + 3) / 4;
    const int gRow   = (N_NODES + 63) / 64;
    const int gPrep  = (S7 + TB - 1) / TB;
    const int gSlice = 8 * ((N_NODES + 15) / 16);   // 4 nodes/wave, 16/block, x8 slices

    // ---- CSR + degree + bounds + fused misc prep (incl. x pooling) ----
    hipMemsetAsync(deg, 0, (size_t)N_NODES * 4, stream);
    hipMemsetAsync(cursor, 0, (size_t)N_NODES * 4, stream);
    hipMemsetAsync(psum, 0, (size_t)N_GRAPHS * JK * 4, stream);
    deg_kernel<<<gDeg, TB, 0, stream>>>(dst, deg, batch, gstart);
    prep_misc<<<gPrep, TB, 0, stream>>>(deg, dis,
                                        W1, a1s, a1d, wes1, wed1,
                                        W2, a2s, a2d, wes2, wed2,
                                        W1T, W2T, x, xbf, gstart, psum);
    scan_bsum<<<NSB, 256, 0, stream>>>(deg, bsum);
    scan_bpre<<<1, 256, 0, stream>>>(bsum, bpre, &off[N_NODES]);
    scan_off<<<NSB, 256, 0, stream>>>(deg, bpre, off);
    csr_fill<<<gE, TB, 0, stream>>>(src, dst, off, cursor, csr_src, csr_sw, dis);

    // ---- GAT layer 1 ----
    esed_x<<<gNwave, TB, 0, stream>>>(x, wes1, wed1, es, ed);
    gat1_fused<<<gFuse, TB, 0, stream>>>(off, csr_src, es, ed, xbf, abf, alpha_fb);
    mfma_gemm<64, 64, 0, 1><<<dim3(gRow, 4), 256, 0, stream>>>(
        (const unsigned short*)abf, 256, W1T, bf1, 256, N_NODES, b1, 1,
        64, 64 * 64, 64);                                   // bf1 = h1a (slice-major)

    // ---- label prop 1 (residual = bf1), slice-partitioned ----
    lp_slice<<<gSlice, TB, 0, stream>>>(off, csr_sw, bf1, bf1, bf2);
    lp_slice<<<gSlice, TB, 0, stream>>>(off, csr_sw, bf2, bf1, bf3);  // bf3 = h1
    esed_h<<<gNwave, TB, 0, stream>>>(bf3, wes2, wed2, es, ed);       // layer-2 logits

    pool_bf<<<dim3(N_GRAPHS, 4), TB, 0, stream>>>(bf3, gstart, psum, 64);

    // ---- GAT layer 2 ----
    mfma_gemm<256, 256, 1, 0><<<dim3(gRow, 1), 256, 0, stream>>>(
        (const unsigned short*)bf3, 256, W2T, bf1, 256, N_NODES, nullptr, 0,
        0, 0, 0);                                           // bf1 = h2 (row-major)
    gat2_fused<<<gFuse, TB, 0, stream>>>(off, csr_src, es, ed, bf1, b2, bf2, alpha_fb); // bf2 = h2a (slice-major)

    // ---- label prop 2 (residual = bf2), slice-partitioned ----
    lp_slice<<<gSlice, TB, 0, stream>>>(off, csr_sw, bf2, bf2, bf1);
    lp_slice<<<gSlice, TB, 0, stream>>>(off, csr_sw, bf1, bf2, abf);  // abf = h2_final

    // ---- pooling (h2) + full head ----
    pool_bf<<<dim3(N_GRAPHS, 4), TB, 0, stream>>>(abf, gstart, psum, 320);
    head_all<<<N_GRAPHS, 256, 0, stream>>>(psum, gstart, clin,
                                           pp_w1, pp_b1, pp_w2, pp_b2,
                                           cl_w1, cl_b1, cl_w2, cl_b2,
                                           h_w1, h_b1, h_w2, h_b2, h_w3, h_b3,
                                           (float*)d_out);
}

// Round 10
// 791.231 us; speedup vs baseline: 1.1755x; 1.0072x over previous
//
#include <hip/hip_runtime.h>
#include <hip/hip_fp16.h>

#define N_NODES 50000
#define N_EDGES 800000
#define N_GRAPHS 128
#define JK 576              // 64 + 256 + 256
#define CAP 192
#define NSB ((N_NODES + 255) / 256)   // scan blocks = 196
#define SLICE_U (N_NODES * 16)        // unsigneds per 32-ch slice block

typedef __attribute__((ext_vector_type(8))) short bf16x8;
typedef __attribute__((ext_vector_type(4))) float f32x4;
typedef __attribute__((ext_vector_type(2))) float float2v;

// ---------- bf16 pack/unpack helpers ----------
__device__ __forceinline__ unsigned f2_to_bf2(float a, float b) {
    unsigned ua = __float_as_uint(a), ub = __float_as_uint(b);
    ua = (ua + 0x7fffu + ((ua >> 16) & 1u)) >> 16;       // RNE
    ub = (ub + 0x7fffu + ((ub >> 16) & 1u)) >> 16;
    return ua | (ub << 16);
}
__device__ __forceinline__ uint2 f4_to_bf4(float4 v) {
    return make_uint2(f2_to_bf2(v.x, v.y), f2_to_bf2(v.z, v.w));
}
__device__ __forceinline__ float4 bf4_to_f4(uint2 u) {
    float4 r;
    r.x = __uint_as_float(u.x << 16);
    r.y = __uint_as_float(u.x & 0xffff0000u);
    r.z = __uint_as_float(u.y << 16);
    r.w = __uint_as_float(u.y & 0xffff0000u);
    return r;
}

// ---------- MFMA GEMM: bf16 out = A_bf16 @ B (BT n-major bf16), fp32 acc ----------
// SLA: A is slice-major (8 x [N][32ch]);  SLC: C written slice-major via LDS
// staging (coalesced 4KB-contiguous runs per slice -- consecutive nodes are
// contiguous in slice-major layout).
template<int BN, int KK, int SLA, int SLC>
__global__ __launch_bounds__(256)
void mfma_gemm(const unsigned short* __restrict__ Abf, int lda,
               const unsigned short* __restrict__ BT,
               unsigned* __restrict__ Cbf, int ldc,
               int M, const float* __restrict__ bias, int relu,
               int a_off, int b_off, int c_off) {
    __shared__ unsigned short As[64][32];
    __shared__ unsigned short Bs[BN][32];
    __shared__ unsigned stg[SLC ? 64 * 32 : 1];   // 8KB staged C-tile (SLC only)
    const int t = threadIdx.x;
    const int wav = t >> 6, lane = t & 63;
    const int quad = lane >> 4, l15 = lane & 15;
    const int m0 = blockIdx.x * 64;
    const int head = blockIdx.y;
    const unsigned short* Ab = Abf + (size_t)head * a_off;
    BT  += (size_t)head * b_off;
    const float* bptr = bias ? bias + (size_t)head * c_off : nullptr;
    unsigned* cbf = Cbf + (((size_t)head * c_off) >> 1);

    f32x4 acc[BN / 16];
#pragma unroll
    for (int i = 0; i < BN / 16; i++) acc[i] = (f32x4){0.f, 0.f, 0.f, 0.f};

    const int arow = t >> 2, aseg = t & 3;
    for (int k0 = 0; k0 < KK; k0 += 32) {
        uint4 av = make_uint4(0, 0, 0, 0);
        int gm = m0 + arow;
        if (gm < M) {
            if (SLA) {
                av = *(const uint4*)&Ab[(size_t)(k0 >> 5) * (N_NODES * 32) +
                                        (size_t)gm * 32 + aseg * 8];
            } else {
                av = *(const uint4*)&Ab[(size_t)gm * lda + k0 + aseg * 8];
            }
        }
        uint4 bv[BN == 256 ? 4 : 1];
        if (BN == 256) {
            const unsigned short* srcb = &BT[(size_t)t * KK + k0];
#pragma unroll
            for (int j = 0; j < 4; j++) bv[j] = *(const uint4*)&srcb[j * 8];
        } else {
            bv[0] = *(const uint4*)&BT[(size_t)arow * KK + k0 + aseg * 8];
        }
        __syncthreads();
        *(uint4*)&As[arow][aseg * 8] = av;
        if (BN == 256) {
#pragma unroll
            for (int j = 0; j < 4; j++) *(uint4*)&Bs[t][j * 8] = bv[j];
        } else {
            *(uint4*)&Bs[arow][aseg * 8] = bv[0];
        }
        __syncthreads();
        bf16x8 afrag = *(const bf16x8*)&As[wav * 16 + l15][quad * 8];
#pragma unroll
        for (int nt = 0; nt < BN / 16; nt++) {
            bf16x8 bfrag = *(const bf16x8*)&Bs[nt * 16 + l15][quad * 8];
            acc[nt] = __builtin_amdgcn_mfma_f32_16x16x32_bf16(afrag, bfrag, acc[nt], 0, 0, 0);
        }
    }
    int rbase_l = wav * 16 + quad * 4;
#pragma unroll
    for (int nt = 0; nt < BN / 16; nt++) {
        int col = nt * 16 + l15;
        float bb = bptr ? bptr[col] : 0.f;
#pragma unroll
        for (int r = 0; r < 4; r++) {
            int row = m0 + rbase_l + r;
            float v = acc[nt][r] + bb;
            if (relu) v = fmaxf(v, 0.f);
            float vp = __shfl_xor(v, 1);
            if (SLC) {
                if (!(l15 & 1))
                    stg[(rbase_l + r) * 32 + nt * 8 + (l15 >> 1)] = f2_to_bf2(v, vp);
            } else if (row < M && !(l15 & 1)) {
                cbf[((size_t)row * ldc + col) >> 1] = f2_to_bf2(v, vp);
            }
        }
    }
    if (SLC) {
        __syncthreads();
        // 2 slices per head-block (64 cols); each slice: 64 rows x 64B contiguous
        int s = t >> 7;              // local slice 0/1
        int k0 = t & 127;
#pragma unroll
        for (int kk = 0; kk < 4; kk++) {
            int k = k0 + kk * 128;               // [0,512) uint2 units
            int r = k >> 3, d = (k & 7) * 2;
            if (m0 + r < M) {
                uint2 v = make_uint2(stg[r * 32 + s * 16 + d], stg[r * 32 + s * 16 + d + 1]);
                *(uint2*)&Cbf[(size_t)(head * 2 + s) * SLICE_U + (size_t)(m0 + r) * 16 + d] = v;
            }
        }
    }
}

// ---------- degree + graph bounds (fused) ----------
__global__ void deg_kernel(const int* __restrict__ dst, int* __restrict__ deg,
                           const int* __restrict__ batch, int* __restrict__ gstart) {
    int t = blockIdx.x * blockDim.x + threadIdx.x;
    if (t < N_EDGES) {
        atomicAdd(&deg[dst[t]], 1);
    } else if (t < N_EDGES + N_NODES) {
        int n = t - N_EDGES;
        int b = batch[n];
        int prev = (n == 0) ? -1 : batch[n - 1];
        for (int g = prev + 1; g <= b; g++) gstart[g] = n;
        if (n == N_NODES - 1)
            for (int g = b + 1; g <= N_GRAPHS; g++) gstart[g] = N_NODES;
    }
}

// ---- fused misc prep: dis | prep_w1 | prep_w2 | W1T | W2T | xbf | pool(x) ----
#define S1 50000
#define S2 50256
#define S3 51280
#define S4 67664
#define S5 133200
#define S6 1733200            // S5 + 50000*32  (xbf pairs)
#define S7 (S6 + 131072)      // + 128 graphs * 4 quarters * 256 threads (x pooling)
__global__ void prep_misc(const int* __restrict__ deg, float* __restrict__ dis,
                          const float* __restrict__ W1, const float* __restrict__ a1s,
                          const float* __restrict__ a1d, float* __restrict__ wes1,
                          float* __restrict__ wed1,
                          const float* __restrict__ W2, const float* __restrict__ a2s,
                          const float* __restrict__ a2d, float* __restrict__ wes2,
                          float* __restrict__ wed2,
                          unsigned short* __restrict__ W1T, unsigned short* __restrict__ W2T,
                          const float* __restrict__ x, unsigned* __restrict__ xbf,
                          const int* __restrict__ gstart, float* __restrict__ psum) {
    int i = blockIdx.x * blockDim.x + threadIdx.x;
    if (i >= S7) return;
    if (i >= S6) {                       // pool x -> psum[:, 0:64]
        int t2 = i - S6;
        int g = t2 >> 10, rem = t2 & 1023;
        int q = rem >> 8, tid = rem & 255;
        int cp = tid & 63, np = tid >> 6;
        int n0 = gstart[g], n1 = gstart[g + 1];
        int len = n1 - n0;
        int ns = n0 + (len * q) / 4, ne = n0 + (len * (q + 1)) / 4;
        float s = 0.f;
        for (int n = ns + np; n < ne; n += 4) s += x[(size_t)n * 64 + cp];
        atomicAdd(&psum[g * JK + cp], s);
    } else if (i >= S5) {                // x -> bf16 (pairs)
        int j = i - S5;
        float2 v = *(const float2*)&x[(size_t)j * 2];
        xbf[j] = f2_to_bf2(v.x, v.y);
    } else if (i >= S4) {                // W2T
        int t2 = i - S4;
        int n = t2 >> 8, c = t2 & 255;
        unsigned u = __float_as_uint(W2[(size_t)c * 256 + n]);
        u = (u + 0x7fffu + ((u >> 16) & 1u)) >> 16;
        W2T[t2] = (unsigned short)u;
    } else if (i >= S3) {                // W1T
        int t2 = i - S3;
        int n = t2 >> 6, c = t2 & 63;
        unsigned u = __float_as_uint(W1[(size_t)c * 256 + n]);
        u = (u + 0x7fffu + ((u >> 16) & 1u)) >> 16;
        W1T[t2] = (unsigned short)u;
    } else if (i >= S2) {                // prep_w2
        int t2 = i - S2;
        int c = t2 >> 2, h = t2 & 3;
        float se = 0.f, sd = 0.f;
        for (int j = 0; j < 64; j++) {
            float w = W2[(size_t)c * 256 + h * 64 + j];
            se += w * a2s[h * 64 + j];
            sd += w * a2d[h * 64 + j];
        }
        wes2[c * 4 + h] = se;
        wed2[c * 4 + h] = sd;
    } else if (i >= S1) {                // prep_w1
        int t2 = i - S1;
        int c = t2 >> 2, h = t2 & 3;
        float se = 0.f, sd = 0.f;
        for (int j = 0; j < 64; j++) {
            float w = W1[(size_t)c * 256 + h * 64 + j];
            se += w * a1s[h * 64 + j];
            sd += w * a1d[h * 64 + j];
        }
        wes1[c * 4 + h] = se;
        wed1[c * 4 + h] = sd;
    } else {                             // dis
        int d = deg[i];
        dis[i] = d > 0 ? rsqrtf((float)d) : 0.f;
    }
}
// ---- hierarchical scan ----
__global__ __launch_bounds__(256) void scan_bsum(const int* __restrict__ deg,
                                                 int* __restrict__ bsum) {
    __shared__ int sd[256];
    int n = blockIdx.x * 256 + threadIdx.x;
    sd[threadIdx.x] = (n < N_NODES) ? deg[n] : 0;
    __syncthreads();
    for (int o = 128; o > 0; o >>= 1) {
        if (threadIdx.x < o) sd[threadIdx.x] += sd[threadIdx.x + o];
        __syncthreads();
    }
    if (threadIdx.x == 0) bsum[blockIdx.x] = sd[0];
}
__global__ __launch_bounds__(256) void scan_bpre(const int* __restrict__ bsum,
                                                 int* __restrict__ bpre,
                                                 int* __restrict__ off_last) {
    __shared__ int sd[256];
    int t = threadIdx.x;
    int v = (t < NSB) ? bsum[t] : 0;
    sd[t] = v;
    __syncthreads();
    for (int o = 1; o < 256; o <<= 1) {
        int u = (t >= o) ? sd[t - o] : 0;
        __syncthreads();
        sd[t] += u;
        __syncthreads();
    }
    if (t < NSB) bpre[t] = sd[t] - v;
    if (t == 255) *off_last = sd[255];
}
__global__ __launch_bounds__(256) void scan_off(const int* __restrict__ deg,
                                                const int* __restrict__ bpre,
                                                int* __restrict__ off) {
    __shared__ int sd[256];
    int n = blockIdx.x * 256 + threadIdx.x;
    int t = threadIdx.x;
    int v = (n < N_NODES) ? deg[n] : 0;
    sd[t] = v;
    __syncthreads();
    for (int o = 1; o < 256; o <<= 1) {
        int u = (t >= o) ? sd[t - o] : 0;
        __syncthreads();
        sd[t] += u;
        __syncthreads();
    }
    if (n < N_NODES) off[n] = bpre[blockIdx.x] + sd[t] - v;
}
// csr_fill also emits packed per-edge records {src:16b | fp16(w):16b} for label
// prop, plus a zero dummy record at N_EDGES (branch-free tail predication).
__global__ void csr_fill(const int* __restrict__ src, const int* __restrict__ dst,
                         const int* __restrict__ off, int* __restrict__ cursor,
                         int* __restrict__ csr_src, unsigned* __restrict__ csr_sw,
                         const float* __restrict__ dis) {
    int e = blockIdx.x * blockDim.x + threadIdx.x;
    if (e == 0) csr_sw[N_EDGES] = 0u;
    if (e >= N_EDGES) return;
    int s = src[e], d = dst[e];
    int pos = off[d] + atomicAdd(&cursor[d], 1);
    csr_src[pos] = s;
    float w = dis[s] * dis[d];
    unsigned hw = (unsigned)__half_as_ushort(__float2half(w));
    csr_sw[pos] = (unsigned)s | (hw << 16);
}

// ---------- es/ed from K=64 fp32 input (x) ----------
__global__ void esed_x(const float* __restrict__ X, const float* __restrict__ wes,
                       const float* __restrict__ wed, float* __restrict__ es,
                       float* __restrict__ ed) {
    int gid = blockIdx.x * blockDim.x + threadIdx.x;
    int n = gid >> 6, lane = threadIdx.x & 63;
    if (n >= N_NODES) return;
    float xv = X[(size_t)n * 64 + lane];
    float4 a = *(const float4*)&wes[lane * 4];
    float4 b = *(const float4*)&wed[lane * 4];
    float4 ps = make_float4(xv * a.x, xv * a.y, xv * a.z, xv * a.w);
    float4 pd = make_float4(xv * b.x, xv * b.y, xv * b.z, xv * b.w);
#pragma unroll
    for (int o = 1; o < 64; o <<= 1) {
        ps.x += __shfl_xor(ps.x, o); ps.y += __shfl_xor(ps.y, o);
        ps.z += __shfl_xor(ps.z, o); ps.w += __shfl_xor(ps.w, o);
        pd.x += __shfl_xor(pd.x, o); pd.y += __shfl_xor(pd.y, o);
        pd.z += __shfl_xor(pd.z, o); pd.w += __shfl_xor(pd.w, o);
    }
    if (lane == 0) {
        *(float4*)&es[n * 4] = ps;
        *(float4*)&ed[n * 4] = pd;
    }
}

// ---------- es/ed for layer 2 from slice-major bf16 h1 ----------
__global__ void esed_h(const unsigned* __restrict__ Hsl, const float* __restrict__ wes,
                       const float* __restrict__ wed, float* __restrict__ es,
                       float* __restrict__ ed) {
    int gid = blockIdx.x * blockDim.x + threadIdx.x;
    int n = gid >> 6, lane = threadIdx.x & 63;
    if (n >= N_NODES) return;
    int sl = lane >> 3;
    uint2 u = *(const uint2*)&Hsl[(size_t)sl * SLICE_U + (size_t)n * 16 + (lane & 7) * 2];
    float4 vv = bf4_to_f4(u);              // channels ch0..ch0+3, ch0 = lane*4
    float v0 = vv.x, v1 = vv.y, v2 = vv.z, v3 = vv.w;
    int ch0 = lane * 4;
    float4 a0 = *(const float4*)&wes[(ch0 + 0) * 4];
    float4 a1 = *(const float4*)&wes[(ch0 + 1) * 4];
    float4 a2 = *(const float4*)&wes[(ch0 + 2) * 4];
    float4 a3 = *(const float4*)&wes[(ch0 + 3) * 4];
    float4 b0 = *(const float4*)&wed[(ch0 + 0) * 4];
    float4 b1 = *(const float4*)&wed[(ch0 + 1) * 4];
    float4 b2 = *(const float4*)&wed[(ch0 + 2) * 4];
    float4 b3 = *(const float4*)&wed[(ch0 + 3) * 4];
    float4 ps, pd;
    ps.x = v0 * a0.x + v1 * a1.x + v2 * a2.x + v3 * a3.x;
    ps.y = v0 * a0.y + v1 * a1.y + v2 * a2.y + v3 * a3.y;
    ps.z = v0 * a0.z + v1 * a1.z + v2 * a2.z + v3 * a3.z;
    ps.w = v0 * a0.w + v1 * a1.w + v2 * a2.w + v3 * a3.w;
    pd.x = v0 * b0.x + v1 * b1.x + v2 * b2.x + v3 * b3.x;
    pd.y = v0 * b0.y + v1 * b1.y + v2 * b2.y + v3 * b3.y;
    pd.z = v0 * b0.z + v1 * b1.z + v2 * b2.z + v3 * b3.z;
    pd.w = v0 * b0.w + v1 * b1.w + v2 * b2.w + v3 * b3.w;
#pragma unroll
    for (int o = 1; o < 64; o <<= 1) {
        ps.x += __shfl_xor(ps.x, o); ps.y += __shfl_xor(ps.y, o);
        ps.z += __shfl_xor(ps.z, o); ps.w += __shfl_xor(ps.w, o);
        pd.x += __shfl_xor(pd.x, o); pd.y += __shfl_xor(pd.y, o);
        pd.w += __shfl_xor(pd.w, o); pd.z += __shfl_xor(pd.z, o);
    }
    if (lane == 0) {
        *(float4*)&es[n * 4] = ps;
        *(float4*)&ed[n * 4] = pd;
    }
}

// ---------- GAT1: fused softmax + bf16-x aggregation (depth-4 pipeline) ----------
__global__ __launch_bounds__(256)
void gat1_fused(const int* __restrict__ off, const int* __restrict__ csr_src,
                const float* __restrict__ es, const float* __restrict__ ed,
                const unsigned* __restrict__ xbf, unsigned* __restrict__ aggx_bf,
                float* __restrict__ alpha_fb) {
    __shared__ float elds[4][CAP * 4];
    __shared__ int   sidx[4][CAP];
    int wav = threadIdx.x >> 6, lane = threadIdx.x & 63;
    int n = blockIdx.x * 4 + wav;
    bool active = n < N_NODES;
    int p0 = 0, p1 = 0;
    float4 ed4 = make_float4(0.f, 0.f, 0.f, 0.f);
    if (active) { p0 = off[n]; p1 = off[n + 1]; ed4 = *(const float4*)&ed[n * 4]; }
    float4 sum = make_float4(0.f, 0.f, 0.f, 0.f);
    for (int p = p0 + lane; p < p1; p += 64) {
        int s = csr_src[p];
        float4 e4 = *(const float4*)&es[s * 4];
        e4.x += ed4.x; e4.y += ed4.y; e4.z += ed4.z; e4.w += ed4.w;
        e4.x = e4.x > 0.f ? e4.x : 0.2f * e4.x;
        e4.y = e4.y > 0.f ? e4.y : 0.2f * e4.y;
        e4.z = e4.z > 0.f ? e4.z : 0.2f * e4.z;
        e4.w = e4.w > 0.f ? e4.w : 0.2f * e4.w;
        e4.x = __expf(e4.x); e4.y = __expf(e4.y); e4.z = __expf(e4.z); e4.w = __expf(e4.w);
        int q = p - p0;
        if (q < CAP) { *(float4*)&elds[wav][q * 4] = e4; sidx[wav][q] = s; }
        else         *(float4*)&alpha_fb[(size_t)p * 4] = e4;
        sum.x += e4.x; sum.y += e4.y; sum.z += e4.z; sum.w += e4.w;
    }
#pragma unroll
    for (int o = 1; o < 64; o <<= 1) {
        sum.x += __shfl_xor(sum.x, o); sum.y += __shfl_xor(sum.y, o);
        sum.z += __shfl_xor(sum.z, o); sum.w += __shfl_xor(sum.w, o);
    }
    float4 rs;
    rs.x = sum.x > 0.f ? 1.f / sum.x : 0.f;
    rs.y = sum.y > 0.f ? 1.f / sum.y : 0.f;
    rs.z = sum.z > 0.f ? 1.f / sum.z : 0.f;
    rs.w = sum.w > 0.f ? 1.f / sum.w : 0.f;
    if (!active) return;
    int eg = lane >> 4, l15 = lane & 15;
    int deg = p1 - p0;
    float4 a0 = make_float4(0.f, 0.f, 0.f, 0.f);
    float4 a1 = a0, a2 = a0, a3 = a0;
    auto fetch = [&](int qq, float4& e4, float4& xv) {
        e4 = make_float4(0.f, 0.f, 0.f, 0.f);
        xv = e4;
        if (qq < deg) {
            int s;
            if (qq < CAP) { s = sidx[wav][qq]; e4 = *(const float4*)&elds[wav][qq * 4]; }
            else { s = csr_src[p0 + qq]; e4 = *(const float4*)&alpha_fb[(size_t)(p0 + qq) * 4]; }
            xv = bf4_to_f4(*(const uint2*)&xbf[(size_t)s * 32 + l15 * 2]);
        }
    };
    int q = eg;
    float4 eA, xA, eB, xB, eC, xC;
    fetch(q, eA, xA);
    fetch(q + 4, eB, xB);
    fetch(q + 8, eC, xC);
    while (q < deg) {
        float4 eD, xD;
        fetch(q + 12, eD, xD);
        a0.x += eA.x * xA.x; a0.y += eA.x * xA.y; a0.z += eA.x * xA.z; a0.w += eA.x * xA.w;
        a1.x += eA.y * xA.x; a1.y += eA.y * xA.y; a1.z += eA.y * xA.z; a1.w += eA.y * xA.w;
        a2.x += eA.z * xA.x; a2.y += eA.z * xA.y; a2.z += eA.z * xA.z; a2.w += eA.z * xA.w;
        a3.x += eA.w * xA.x; a3.y += eA.w * xA.y; a3.z += eA.w * xA.z; a3.w += eA.w * xA.w;
        eA = eB; xA = xB; eB = eC; xB = xC; eC = eD; xC = xD;
        q += 4;
    }
#pragma unroll
    for (int o = 16; o < 64; o <<= 1) {
        a0.x += __shfl_xor(a0.x, o); a0.y += __shfl_xor(a0.y, o);
        a0.z += __shfl_xor(a0.z, o); a0.w += __shfl_xor(a0.w, o);
        a1.x += __shfl_xor(a1.x, o); a1.y += __shfl_xor(a1.y, o);
        a1.z += __shfl_xor(a1.z, o); a1.w += __shfl_xor(a1.w, o);
        a2.x += __shfl_xor(a2.x, o); a2.y += __shfl_xor(a2.y, o);
        a2.z += __shfl_xor(a2.z, o); a2.w += __shfl_xor(a2.w, o);
        a3.x += __shfl_xor(a3.x, o); a3.y += __shfl_xor(a3.y, o);
        a3.z += __shfl_xor(a3.z, o); a3.w += __shfl_xor(a3.w, o);
    }
    if (eg == 0) {
        a0.x *= rs.x; a0.y *= rs.x; a0.z *= rs.x; a0.w *= rs.x;
        a1.x *= rs.y; a1.y *= rs.y; a1.z *= rs.y; a1.w *= rs.y;
        a2.x *= rs.z; a2.y *= rs.z; a2.z *= rs.z; a2.w *= rs.z;
        a3.x *= rs.w; a3.y *= rs.w; a3.z *= rs.w; a3.w *= rs.w;
        size_t b = (size_t)n * 128 + l15 * 2;
        *(uint2*)&aggx_bf[b +  0] = f4_to_bf4(a0);
        *(uint2*)&aggx_bf[b + 32] = f4_to_bf4(a1);
        *(uint2*)&aggx_bf[b + 64] = f4_to_bf4(a2);
        *(uint2*)&aggx_bf[b + 96] = f4_to_bf4(a3);
    }
}

// ---------- GAT2: fused softmax + bf16 gather; LDS-staged coalesced slice write ----
// N_NODES = 12500*4 exactly -> every block's 4 nodes are valid (no tail guard).
__global__ __launch_bounds__(256)
void gat2_fused(const int* __restrict__ off, const int* __restrict__ csr_src,
                const float* __restrict__ es, const float* __restrict__ ed,
                const unsigned* __restrict__ H2bf, const float* __restrict__ bias,
                unsigned* __restrict__ outbf, float* __restrict__ alpha_fb) {
    __shared__ float elds[4][CAP * 4];
    __shared__ int   sidx[4][CAP];
    __shared__ unsigned stg[4][128];
    int wav = threadIdx.x >> 6, lane = threadIdx.x & 63;
    int n = blockIdx.x * 4 + wav;
    int p0 = off[n], p1 = off[n + 1];
    float4 ed4 = *(const float4*)&ed[n * 4];
    float4 sum = make_float4(0.f, 0.f, 0.f, 0.f);
    for (int p = p0 + lane; p < p1; p += 64) {
        int s = csr_src[p];
        float4 e4 = *(const float4*)&es[s * 4];
        e4.x += ed4.x; e4.y += ed4.y; e4.z += ed4.z; e4.w += ed4.w;
        e4.x = e4.x > 0.f ? e4.x : 0.2f * e4.x;
        e4.y = e4.y > 0.f ? e4.y : 0.2f * e4.y;
        e4.z = e4.z > 0.f ? e4.z : 0.2f * e4.z;
        e4.w = e4.w > 0.f ? e4.w : 0.2f * e4.w;
        e4.x = __expf(e4.x); e4.y = __expf(e4.y); e4.z = __expf(e4.z); e4.w = __expf(e4.w);
        int q = p - p0;
        if (q < CAP) { *(float4*)&elds[wav][q * 4] = e4; sidx[wav][q] = s; }
        else         *(float4*)&alpha_fb[(size_t)p * 4] = e4;
        sum.x += e4.x; sum.y += e4.y; sum.z += e4.z; sum.w += e4.w;
    }
#pragma unroll
    for (int o = 1; o < 64; o <<= 1) {
        sum.x += __shfl_xor(sum.x, o); sum.y += __shfl_xor(sum.y, o);
        sum.z += __shfl_xor(sum.z, o); sum.w += __shfl_xor(sum.w, o);
    }
    int half = lane >> 5, l = lane & 31;
    int hh = l >> 3;
    float sh = (hh == 0) ? sum.x : (hh == 1) ? sum.y : (hh == 2) ? sum.z : sum.w;
    float rsh = sh > 0.f ? 1.f / sh : 0.f;
    int deg = p1 - p0;
    float acc[8];
#pragma unroll
    for (int j = 0; j < 8; j++) acc[j] = 0.f;
    auto fetch = [&](int qq, float& al, uint4& rr) {
        al = 0.f;
        rr = make_uint4(0, 0, 0, 0);
        if (qq < deg) {
            int s;
            if (qq < CAP) { s = sidx[wav][qq]; al = elds[wav][qq * 4 + hh]; }
            else { s = csr_src[p0 + qq]; al = alpha_fb[(size_t)(p0 + qq) * 4 + hh]; }
            rr = *(const uint4*)&H2bf[(size_t)s * 128 + l * 4];
        }
    };
    int q = half;
    float aA, aB, aC;
    uint4 rA, rB, rC;
    fetch(q, aA, rA);
    fetch(q + 2, aB, rB);
    fetch(q + 4, aC, rC);
    while (q < deg) {
        float aD; uint4 rD;
        fetch(q + 6, aD, rD);
        float4 f0 = bf4_to_f4(make_uint2(rA.x, rA.y));
        float4 f1 = bf4_to_f4(make_uint2(rA.z, rA.w));
        acc[0] += aA * f0.x; acc[1] += aA * f0.y; acc[2] += aA * f0.z; acc[3] += aA * f0.w;
        acc[4] += aA * f1.x; acc[5] += aA * f1.y; acc[6] += aA * f1.z; acc[7] += aA * f1.w;
        aA = aB; rA = rB; aB = aC; rB = rC; aC = aD; rC = rD;
        q += 2;
    }
#pragma unroll
    for (int j = 0; j < 8; j++) acc[j] += __shfl_xor(acc[j], 32);
    if (half == 0) {
        float4 b0 = *(const float4*)&bias[l * 8];
        float4 b1 = *(const float4*)&bias[l * 8 + 4];
        float4 o0, o1;
        o0.x = fmaxf(acc[0] * rsh + b0.x, 0.f);
        o0.y = fmaxf(acc[1] * rsh + b0.y, 0.f);
        o0.z = fmaxf(acc[2] * rsh + b0.z, 0.f);
        o0.w = fmaxf(acc[3] * rsh + b0.w, 0.f);
        o1.x = fmaxf(acc[4] * rsh + b1.x, 0.f);
        o1.y = fmaxf(acc[5] * rsh + b1.y, 0.f);
        o1.z = fmaxf(acc[6] * rsh + b1.z, 0.f);
        o1.w = fmaxf(acc[7] * rsh + b1.w, 0.f);
        uint2 w0 = f4_to_bf4(o0), w1 = f4_to_bf4(o1);
        *(uint4*)&stg[wav][l * 4] = make_uint4(w0.x, w0.y, w1.x, w1.y);
    }
    __syncthreads();
    // block-cooperative slice-major write: 256B contiguous per slice per block
    {
        int t = threadIdx.x;
        int s = t >> 5;              // slice 0..7
        int j = t & 31;              // uint2 index: 4 nodes x 16 dwords = 32 uint2
        int node = j >> 3;
        int dw = (j & 7) * 2;
        uint2 v = make_uint2(stg[node][s * 16 + dw], stg[node][s * 16 + dw + 1]);
        *(uint2*)&outbf[(size_t)s * SLICE_U + (size_t)(blockIdx.x * 4 + node) * 16 + dw] = v;
    }
}

// ---------- label prop, slice-partitioned, 4 nodes/wave, packed 4B records ----------
// lane = nsub*16 + e*4 + seg : 4 nodes x 4 edges x 4 x 16B segments.
// Record = {src:16b | fp16(dis[s]*dis[d]):16b}; dummy zero record at N_EDGES.
// Unroll-by-2 ping-pong pipeline (no rotation moves) + packed fp32 accumulate.
__global__ __launch_bounds__(256)
void lp_slice(const int* __restrict__ off, const unsigned* __restrict__ csr_sw,
              const unsigned* __restrict__ in_sl,
              const unsigned* __restrict__ res_sl, unsigned* __restrict__ out_sl) {
    int wav = threadIdx.x >> 6, lane = threadIdx.x & 63;
    int sl = blockIdx.x & 7, chunk = blockIdx.x >> 3;
    int n0c = chunk * 16 + wav * 4;
    int nsub = lane >> 4, e = (lane >> 2) & 3, seg = lane & 3;
    int n = n0c + nsub;
    int p0 = 0, p1 = 0;
    if (n < N_NODES) { p0 = off[n]; p1 = off[n + 1]; }
    int m = (p1 - p0 + 3) >> 2;
    m = max(m, __shfl_xor(m, 16));
    m = max(m, __shfl_xor(m, 32));
    const unsigned* base = in_sl + (size_t)sl * SLICE_U;
    float2v a01 = {0.f, 0.f}, a23 = {0.f, 0.f}, a45 = {0.f, 0.f}, a67 = {0.f, 0.f};
    int p = p0 + e;
#define LP_ACC(rr, dd)                                                                        \
    {                                                                                         \
        float nwf = __half2float(__ushort_as_half((unsigned short)((rr) >> 16)));             \
        float2v nw2 = {nwf, nwf};                                                             \
        float2v f01, f23, f45, f67;                                                           \
        f01.x = __uint_as_float((dd).x << 16); f01.y = __uint_as_float((dd).x & 0xffff0000u); \
        f23.x = __uint_as_float((dd).y << 16); f23.y = __uint_as_float((dd).y & 0xffff0000u); \
        f45.x = __uint_as_float((dd).z << 16); f45.y = __uint_as_float((dd).z & 0xffff0000u); \
        f67.x = __uint_as_float((dd).w << 16); f67.y = __uint_as_float((dd).w & 0xffff0000u); \
        a01 += nw2 * f01; a23 += nw2 * f23; a45 += nw2 * f45; a67 += nw2 * f67;               \
    }
    if (m > 0) {
        int pe0 = (p < p1) ? p : N_EDGES;
        unsigned rA = csr_sw[pe0];
        int pe1 = (p + 4 < p1) ? p + 4 : N_EDGES;
        unsigned rB = csr_sw[pe1];
        uint4 dA = *(const uint4*)&base[((rA & 0xffffu) << 4) + (seg << 2)];
        int i = 0;
        for (; i + 2 <= m; i += 2) {
            int pe2 = (p + 8 < p1) ? p + 8 : N_EDGES;
            unsigned rC = csr_sw[pe2];                                            // rec i+2
            uint4 dB = *(const uint4*)&base[((rB & 0xffffu) << 4) + (seg << 2)];  // row i+1
            LP_ACC(rA, dA);                                                       // edge i
            int pe3 = (p + 12 < p1) ? p + 12 : N_EDGES;
            unsigned rD = csr_sw[pe3];                                            // rec i+3
            dA = *(const uint4*)&base[((rC & 0xffffu) << 4) + (seg << 2)];        // row i+2
            LP_ACC(rB, dB);                                                       // edge i+1
            rA = rC; rB = rD;
            p += 8;
        }
        if (i < m) LP_ACC(rA, dA);                                                // odd tail
    }
#undef LP_ACC
#pragma unroll
    for (int o = 4; o <= 8; o <<= 1) {
        a01.x += __shfl_xor(a01.x, o); a01.y += __shfl_xor(a01.y, o);
        a23.x += __shfl_xor(a23.x, o); a23.y += __shfl_xor(a23.y, o);
        a45.x += __shfl_xor(a45.x, o); a45.y += __shfl_xor(a45.y, o);
        a67.x += __shfl_xor(a67.x, o); a67.y += __shfl_xor(a67.y, o);
    }
    if (((lane & 12) == 0) && n < N_NODES) {   // e == 0: 16 lanes = 4 nodes x 4 segs
        size_t a = (size_t)sl * SLICE_U + (size_t)n * 16 + (seg << 2);
        uint4 rr = *(const uint4*)&res_sl[a];
        float4 r0 = bf4_to_f4(make_uint2(rr.x, rr.y));
        float4 r1 = bf4_to_f4(make_uint2(rr.z, rr.w));
        float4 o0, o1;
        o0.x = fminf(fmaxf(0.5f * a01.x + 0.5f * r0.x, 0.f), 1.f);
        o0.y = fminf(fmaxf(0.5f * a01.y + 0.5f * r0.y, 0.f), 1.f);
        o0.z = fminf(fmaxf(0.5f * a23.x + 0.5f * r0.z, 0.f), 1.f);
        o0.w = fminf(fmaxf(0.5f * a23.y + 0.5f * r0.w, 0.f), 1.f);
        o1.x = fminf(fmaxf(0.5f * a45.x + 0.5f * r1.x, 0.f), 1.f);
        o1.y = fminf(fmaxf(0.5f * a45.y + 0.5f * r1.y, 0.f), 1.f);
        o1.z = fminf(fmaxf(0.5f * a67.x + 0.5f * r1.z, 0.f), 1.f);
        o1.w = fminf(fmaxf(0.5f * a67.y + 0.5f * r1.w, 0.f), 1.f);
        uint2 w0 = f4_to_bf4(o0), w1 = f4_to_bf4(o1);
        *(uint4*)&out_sl[a] = make_uint4(w0.x, w0.y, w1.x, w1.y);
    }
}

// ---------- bf16 pool (slice-major input) ----------
__global__ void pool_bf(const unsigned* __restrict__ buf, const int* __restrict__ gstart,
                        float* __restrict__ psum, int colOff) {
    int g = blockIdx.x, q = blockIdx.y;
    int n0 = gstart[g], n1 = gstart[g + 1];
    int len = n1 - n0;
    int ns = n0 + (len * q) / 4, ne = n0 + (len * (q + 1)) / 4;
    int cp = threadIdx.x & 127;
    int np = threadIdx.x >> 7;
    size_t sbase = (size_t)(cp >> 4) * SLICE_U + (cp & 15);
    float s0 = 0.f, s1 = 0.f;
    for (int n = ns + np; n < ne; n += 2) {
        unsigned u = buf[sbase + (size_t)n * 16];
        s0 += __uint_as_float(u << 16);
        s1 += __uint_as_float(u & 0xffff0000u);
    }
    atomicAdd(&psum[g * JK + colOff + cp * 2 + 0], s0);
    atomicAdd(&psum[g * JK + colOff + cp * 2 + 1], s1);
}

// ---------- full MLP head: one block per graph ----------
__global__ __launch_bounds__(256)
void head_all(const float* __restrict__ psum, const int* __restrict__ gstart,
              const float* __restrict__ clin,
              const float* __restrict__ pp_w1, const float* __restrict__ pp_b1,
              const float* __restrict__ pp_w2, const float* __restrict__ pp_b2,
              const float* __restrict__ cl_w1, const float* __restrict__ cl_b1,
              const float* __restrict__ cl_w2, const float* __restrict__ cl_b2,
              const float* __restrict__ h_w1, const float* __restrict__ h_b1,
              const float* __restrict__ h_w2, const float* __restrict__ h_b2,
              const float* __restrict__ h_w3, const float* __restrict__ h_b3,
              float* __restrict__ out) {
    __shared__ float zin[JK];
    __shared__ float z1[256];
    __shared__ float zcl[32];
    __shared__ float zc[64];
    __shared__ float z[160];
    __shared__ float z3[64];
    __shared__ float z4[32];
    __shared__ float part[128];
    int g = blockIdx.x, t = threadIdx.x;
    int len = gstart[g + 1] - gstart[g];
    float inv = 1.f / (float)(len > 1 ? len : 1);
    for (int k = t; k < JK; k += 256) zin[k] = psum[g * JK + k] * inv;
    if (t < 32) zcl[t] = clin[g * 32 + t];
    __syncthreads();
    {
        float acc = pp_b1[t];
#pragma unroll 8
        for (int k = 0; k < JK; k++) acc += zin[k] * pp_w1[k * 256 + t];
        z1[t] = fmaxf(acc, 0.f);
    }
    __syncthreads();
    int m = t & 127, half = t >> 7;
    {
        float acc = 0.f;
        int k0 = half * 128;
#pragma unroll 8
        for (int k = k0; k < k0 + 128; k++) acc += z1[k] * pp_w2[k * 128 + m];
        if (half) part[m] = acc;
        __syncthreads();
        if (!half) z[m] = acc + part[m] + pp_b2[m];
    }
    if (t < 64) {
        float acc = cl_b1[t];
#pragma unroll
        for (int k = 0; k < 32; k++) acc += zcl[k] * cl_w1[k * 64 + t];
        zc[t] = fmaxf(acc, 0.f);
    }
    __syncthreads();
    if (t < 32) {
        float acc = cl_b2[t];
#pragma unroll
        for (int k = 0; k < 64; k++) acc += zc[k] * cl_w2[k * 32 + t];
        z[128 + t] = acc;
    }
    __syncthreads();
    if (t < 64) {
        float acc = h_b1[t];
#pragma unroll 8
        for (int k = 0; k < 160; k++) acc += z[k] * h_w1[k * 64 + t];
        z3[t] = fmaxf(acc, 0.f);
    }
    __syncthreads();
    if (t < 32) {
        float acc = h_b2[t];
#pragma unroll
        for (int k = 0; k < 64; k++) acc += z3[k] * h_w2[k * 32 + t];
        z4[t] = fmaxf(acc, 0.f);
    }
    __syncthreads();
    if (t < 2) {
        float acc = h_b3[t];
#pragma unroll
        for (int k = 0; k < 32; k++) acc += z4[k] * h_w3[k * 2 + t];
        out[g * 2 + t] = acc;
    }
}

// ---------- launch ----------
extern "C" void kernel_launch(void* const* d_in, const int* in_sizes, int n_in,
                              void* d_out, int out_size, void* d_ws, size_t ws_size,
                              hipStream_t stream) {
    const float* x     = (const float*)d_in[0];
    const int*   ei    = (const int*)d_in[1];
    const int*   batch = (const int*)d_in[2];
    const float* clin  = (const float*)d_in[3];
    const float* W1  = (const float*)d_in[4];
    const float* a1s = (const float*)d_in[5];
    const float* a1d = (const float*)d_in[6];
    const float* b1  = (const float*)d_in[7];
    const float* W2  = (const float*)d_in[8];
    const float* a2s = (const float*)d_in[9];
    const float* a2d = (const float*)d_in[10];
    const float* b2  = (const float*)d_in[11];
    const float* pp_w1 = (const float*)d_in[12];
    const float* pp_b1 = (const float*)d_in[13];
    const float* pp_w2 = (const float*)d_in[14];
    const float* pp_b2 = (const float*)d_in[15];
    const float* cl_w1 = (const float*)d_in[16];
    const float* cl_b1 = (const float*)d_in[17];
    const float* cl_w2 = (const float*)d_in[18];
    const float* cl_b2 = (const float*)d_in[19];
    const float* h_w1  = (const float*)d_in[20];
    const float* h_b1  = (const float*)d_in[21];
    const float* h_w2  = (const float*)d_in[22];
    const float* h_b2  = (const float*)d_in[23];
    const float* h_w3  = (const float*)d_in[24];
    const float* h_b3  = (const float*)d_in[25];

    const int* src = ei;
    const int* dst = ei + N_EDGES;

    char* p = (char*)d_ws;
    auto carve = [&](size_t bytes) -> char* {
        char* r = p;
        p += (bytes + 255) & ~(size_t)255;
        return r;
    };
    const size_t NBH = (size_t)N_NODES * 256 * 2;    // bf16 node buffer
    unsigned* abf  = (unsigned*)carve(NBH);          // aggx, later h2_final
    unsigned* bf1  = (unsigned*)carve(NBH);
    unsigned* bf2  = (unsigned*)carve(NBH);
    unsigned* bf3  = (unsigned*)carve(NBH);
    unsigned* xbf  = (unsigned*)carve((size_t)N_NODES * 32 * 4);  // bf16 x copy
    float* alpha_fb  = (float*)carve((size_t)N_EDGES * 4 * 4);
    int*   csr_src   = (int*)carve((size_t)N_EDGES * 4);
    unsigned* csr_sw = (unsigned*)carve((size_t)(N_EDGES + 1) * 4); // packed {src,hw} + dummy
    int*   off       = (int*)carve((size_t)(N_NODES + 1) * 4);
    int*   deg       = (int*)carve((size_t)N_NODES * 4);
    int*   cursor    = (int*)carve((size_t)N_NODES * 4);
    int*   bsum      = (int*)carve((size_t)NSB * 4);
    int*   bpre      = (int*)carve((size_t)NSB * 4);
    float* dis       = (float*)carve((size_t)N_NODES * 4);
    float* es        = (float*)carve((size_t)N_NODES * 4 * 4);
    float* ed        = (float*)carve((size_t)N_NODES * 4 * 4);
    float* wes1      = (float*)carve((size_t)64 * 4 * 4);
    float* wed1      = (float*)carve((size_t)64 * 4 * 4);
    float* wes2      = (float*)carve((size_t)256 * 4 * 4);
    float* wed2      = (float*)carve((size_t)256 * 4 * 4);
    unsigned short* W1T = (unsigned short*)carve((size_t)256 * 64 * 2);
    unsigned short* W2T = (unsigned short*)carve((size_t)256 * 256 * 2);
    int*   gstart    = (int*)carve((size_t)(N_GRAPHS + 1) * 4);
    float* psum      = (float*)carve((size_t)N_GRAPHS * JK * 4);

    const int TB = 256;
    const int gE     = (N_EDGES + TB - 1) / TB;
    const int gDeg   = (N_EDGES + N_NODES + TB - 1) / TB;
    const int gNwave = (N_NODES * 64 + TB - 1) / TB;
    const int gFuse  = (N_NODES + 3) / 4;
    const int gRow   = (N_NODES + 63) / 64;
    const int gPrep  = (S7 + TB - 1) / TB;
    const int gSlice = 8 * ((N_NODES + 15) / 16);   // 4 nodes/wave, 16/block, x8 slices

    // ---- CSR + degree + bounds + fused misc prep (incl. x pooling) ----
    hipMemsetAsync(deg, 0, (size_t)N_NODES * 4, stream);
    hipMemsetAsync(cursor, 0, (size_t)N_NODES * 4, stream);
    hipMemsetAsync(psum, 0, (size_t)N_GRAPHS * JK * 4, stream);
    deg_kernel<<<gDeg, TB, 0, stream>>>(dst, deg, batch, gstart);
    prep_misc<<<gPrep, TB, 0, stream>>>(deg, dis,
                                        W1, a1s, a1d, wes1, wed1,
                                        W2, a2s, a2d, wes2, wed2,
                                        W1T, W2T, x, xbf, gstart, psum);
    scan_bsum<<<NSB, 256, 0, stream>>>(deg, bsum);
    scan_bpre<<<1, 256, 0, stream>>>(bsum, bpre, &off[N_NODES]);
    scan_off<<<NSB, 256, 0, stream>>>(deg, bpre, off);
    csr_fill<<<gE, TB, 0, stream>>>(src, dst, off, cursor, csr_src, csr_sw, dis);

    // ---- GAT layer 1 ----
    esed_x<<<gNwave, TB, 0, stream>>>(x, wes1, wed1, es, ed);
    gat1_fused<<<gFuse, TB, 0, stream>>>(off, csr_src, es, ed, xbf, abf, alpha_fb);
    mfma_gemm<64, 64, 0, 1><<<dim3(gRow, 4), 256, 0, stream>>>(
        (const unsigned short*)abf, 256, W1T, bf1, 256, N_NODES, b1, 1,
        64, 64 * 64, 64);                                   // bf1 = h1a (slice-major)

    // ---- label prop 1 (residual = bf1), slice-partitioned ----
    lp_slice<<<gSlice, TB, 0, stream>>>(off, csr_sw, bf1, bf1, bf2);
    lp_slice<<<gSlice, TB, 0, stream>>>(off, csr_sw, bf2, bf1, bf3);  // bf3 = h1
    esed_h<<<gNwave, TB, 0, stream>>>(bf3, wes2, wed2, es, ed);       // layer-2 logits

    pool_bf<<<dim3(N_GRAPHS, 4), TB, 0, stream>>>(bf3, gstart, psum, 64);

    // ---- GAT layer 2 ----
    mfma_gemm<256, 256, 1, 0><<<dim3(gRow, 1), 256, 0, stream>>>(
        (const unsigned short*)bf3, 256, W2T, bf1, 256, N_NODES, nullptr, 0,
        0, 0, 0);                                           // bf1 = h2 (row-major)
    gat2_fused<<<gFuse, TB, 0, stream>>>(off, csr_src, es, ed, bf1, b2, bf2, alpha_fb); // bf2 = h2a (slice-major)

    // ---- label prop 2 (residual = bf2), slice-partitioned ----
    lp_slice<<<gSlice, TB, 0, stream>>>(off, csr_sw, bf2, bf2, bf1);
    lp_slice<<<gSlice, TB, 0, stream>>>(off, csr_sw, bf1, bf2, abf);  // abf = h2_final

    // ---- pooling (h2) + full head ----
    pool_bf<<<dim3(N_GRAPHS, 4), TB, 0, stream>>>(abf, gstart, psum, 320);
    head_all<<<N_GRAPHS, 256, 0, stream>>>(psum, gstart, clin,
                                           pp_w1, pp_b1, pp_w2, pp_b2,
                                           cl_w1, cl_b1, cl_w2, cl_b2,
                                           h_w1, h_b1, h_w2, h_b2, h_w3, h_b3,
                                           (float*)d_out);
}